// Round 9
// baseline (419.072 us; speedup 1.0000x reference)
//
#include <hip/hip_runtime.h>

typedef unsigned short u16;
typedef unsigned int u32;
typedef float f32x4 __attribute__((ext_vector_type(4)));
typedef float f32x16 __attribute__((ext_vector_type(16)));
typedef __bf16 bf16x8 __attribute__((ext_vector_type(8)));
typedef short s16x8 __attribute__((ext_vector_type(8)));
typedef short s16x4 __attribute__((ext_vector_type(4)));
typedef u32 u32x4 __attribute__((ext_vector_type(4)));

#define MFMA16(a, b, c) __builtin_amdgcn_mfma_f32_16x16x32_bf16((a), (b), (c), 0, 0, 0)
#define MFMA32(a, b, c) __builtin_amdgcn_mfma_f32_32x32x16_bf16((a), (b), (c), 0, 0, 0)

typedef const __attribute__((address_space(1))) void* gas1_t;
typedef __attribute__((address_space(3))) void* las3_t;
#define GLDS16(g, l) __builtin_amdgcn_global_load_lds((gas1_t)(g), (las3_t)(l), 16, 0, 0)

static __device__ __forceinline__ u16 f2bf(float f) {
  u32 u = __builtin_bit_cast(u32, f);
  u += 0x7FFFu + ((u >> 16) & 1u);
  return (u16)(u >> 16);
}
static __device__ __forceinline__ u32 cvtpk(float lo, float hi) {
  u32 r;
  asm("v_cvt_pk_bf16_f32 %0, %1, %2" : "=v"(r) : "v"(lo), "v"(hi));
  return r;
}
static __device__ __forceinline__ float gelu_t(float g) {
  float u = 0.7978845608f * (g + 0.044715f * g * g * g);
  float e = __expf(2.0f * u);
  float t = 1.0f - 2.0f / (e + 1.0f);
  return 0.5f * g * (1.0f + t);
}

// ---- ALL weight preprocessing in one launch (4096 blocks) ----
__global__ __launch_bounds__(256) void prep_weights(const float* __restrict__ Wq,
                                                    const float* __restrict__ Wk,
                                                    const float* __restrict__ Wv,
                                                    const float* __restrict__ Wo,
                                                    const float* __restrict__ W1,
                                                    const float* __restrict__ W2,
                                                    u16* __restrict__ wqt,
                                                    u16* __restrict__ wkvt,
                                                    u16* __restrict__ wot,
                                                    u16* __restrict__ w1i,
                                                    u16* __restrict__ w2t, float qsc) {
  __shared__ u16 t[64][72];
  const int id = blockIdx.x;
  const int tid = threadIdx.x;
  auto tileT = [&](const float* in, u16* out, int K, int N, int k0, int n0, float scale) {
#pragma unroll
    for (int i = 0; i < 16; ++i) {
      int idx = tid + i * 256;
      int r = idx >> 6, c = idx & 63;
      t[r][c] = f2bf(in[(size_t)(k0 + r) * N + n0 + c] * scale);
    }
    __syncthreads();
#pragma unroll
    for (int i = 0; i < 16; ++i) {
      int idx = tid + i * 256;
      int r = idx >> 6, c = idx & 63;
      out[(size_t)(n0 + r) * K + k0 + c] = t[c][r];
    }
  };
  if (id < 256) {
    tileT(Wq, wqt, 1024, 1024, (id & 15) * 64, (id >> 4) * 64, qsc);
  } else if (id < 512) {
    int i2 = id - 256;
    tileT(Wk, wkvt, 1024, 1024, (i2 & 15) * 64, (i2 >> 4) * 64, 1.0f);
  } else if (id < 768) {
    int i2 = id - 512;
    tileT(Wv, wkvt + 1024 * 1024, 1024, 1024, (i2 & 15) * 64, (i2 >> 4) * 64, 1.0f);
  } else if (id < 1024) {
    int i2 = id - 768;
    tileT(Wo, wot, 1024, 1024, (i2 & 15) * 64, (i2 >> 4) * 64, 1.0f);
  } else if (id < 3072) {
    int i2 = id - 1024;
    int k0 = (i2 & 15) * 64, n0 = (i2 >> 4) * 64;
#pragma unroll
    for (int i = 0; i < 16; ++i) {
      int idx = tid + i * 256;
      int r = idx >> 6, c = idx & 63;
      int np = n0 + c;
      int orig = ((np >> 5) << 4) + (np & 15) + (((np >> 4) & 1) << 12);
      t[r][c] = f2bf(W1[(size_t)(k0 + r) * 8192 + orig]);
    }
    __syncthreads();
#pragma unroll
    for (int i = 0; i < 16; ++i) {
      int idx = tid + i * 256;
      int r = idx >> 6, c = idx & 63;
      w1i[(size_t)(n0 + r) * 1024 + k0 + c] = t[c][r];
    }
  } else {
    int i3 = id - 3072;
    tileT(W2, w2t, 4096, 1024, (i3 & 63) * 64, (i3 >> 6) * 64, 1.0f);
  }
}

// ---- fused LayerNorm: blocks 0..4095 = q rows; 4096..12287 = kv rows ----
__global__ __launch_bounds__(256) void ln_fused(const float* __restrict__ xq,
                                                const float* __restrict__ xkv,
                                                const float* __restrict__ scq,
                                                const float* __restrict__ biq,
                                                const float* __restrict__ sckv,
                                                const float* __restrict__ bikv,
                                                u16* __restrict__ outq,
                                                u16* __restrict__ outkv) {
  const int id = blockIdx.x;
  const bool isq = id < 4096;
  const int row = isq ? id : id - 4096;
  const float* x = isq ? xq : xkv;
  const float* sc = isq ? scq : sckv;
  const float* bi = isq ? biq : bikv;
  u16* out = isq ? outq : outkv;
  int tid = threadIdx.x;
  float4 v = ((const float4*)(x + (size_t)row * 1024))[tid];
  float s = v.x + v.y + v.z + v.w;
  float s2 = v.x * v.x + v.y * v.y + v.z * v.z + v.w * v.w;
  for (int m = 1; m < 64; m <<= 1) {
    s += __shfl_xor(s, m);
    s2 += __shfl_xor(s2, m);
  }
  __shared__ float rs[4], rs2[4];
  int wave = tid >> 6, lane = tid & 63;
  if (lane == 0) { rs[wave] = s; rs2[wave] = s2; }
  __syncthreads();
  s = rs[0] + rs[1] + rs[2] + rs[3];
  s2 = rs2[0] + rs2[1] + rs2[2] + rs2[3];
  float mu = s * (1.0f / 1024.0f);
  float var = s2 * (1.0f / 1024.0f) - mu * mu;
  float inv = rsqrtf(var + 1e-6f);
  float4 scv = ((const float4*)sc)[tid];
  float4 biv = ((const float4*)bi)[tid];
  s16x4 o;
  o[0] = (short)f2bf((v.x - mu) * inv * scv.x + biv.x);
  o[1] = (short)f2bf((v.y - mu) * inv * scv.y + biv.y);
  o[2] = (short)f2bf((v.z - mu) * inv * scv.z + biv.z);
  o[3] = (short)f2bf((v.w - mu) * inv * scv.w + biv.w);
  *(s16x4*)(out + (size_t)row * 1024 + tid * 4) = o;
}

// ---- 128x128 GEMM (2-phase, swizzled, 0 conflicts) ----
template <int MODE>
__global__ __launch_bounds__(256) void gemm_nt(const u16* __restrict__ A,
                                               const u16* __restrict__ Bt,
                                               const float* __restrict__ bias,
                                               const float* __restrict__ resid,
                                               void* __restrict__ Cout,
                                               int M, int N, int K, float bias_scale) {
  __shared__ u16 As[128 * 64];
  __shared__ u16 Bs[128 * 64];
  const int nbx = gridDim.x;
  const int nwg = nbx * gridDim.y;
  const int wg0 = blockIdx.y * nbx + blockIdx.x;
  const int wg = (nwg & 7) ? wg0 : (wg0 & 7) * (nwg >> 3) + (wg0 >> 3);
  const int m0 = (wg % nbx) * 128, n0 = (wg / nbx) * 128;
  const int tid = threadIdx.x;
  const int lane = tid & 63, wave = tid >> 6;
  const int wm = (wave >> 1) * 64, wn = (wave & 1) * 64;
  const int lr = lane & 15, hi4 = lane >> 4;
  f32x4 acc[4][4] = {};
  for (int k0 = 0; k0 < K; k0 += 64) {
#pragma unroll
    for (int i = 0; i < 4; ++i) {
      int s = i * 256 + tid;
      int r = s >> 3, slot = s & 7;
      int gslot = slot ^ (r & 7);
      int ldst = (i * 256 + wave * 64) * 8;
      GLDS16(A + (size_t)(m0 + r) * K + k0 + gslot * 8, &As[ldst]);
      GLDS16(Bt + (size_t)(n0 + r) * K + k0 + gslot * 8, &Bs[ldst]);
    }
    __syncthreads();
#pragma unroll
    for (int ks = 0; ks < 2; ++ks) {
      const int sl = ((ks * 4 + hi4) ^ (lr & 7)) * 8;
      bf16x8 af[4], bfr[4];
#pragma unroll
      for (int t = 0; t < 4; ++t) {
        af[t] = __builtin_bit_cast(bf16x8, *(const s16x8*)&As[(wm + t * 16 + lr) * 64 + sl]);
        bfr[t] = __builtin_bit_cast(bf16x8, *(const s16x8*)&Bs[(wn + t * 16 + lr) * 64 + sl]);
      }
#pragma unroll
      for (int mt = 0; mt < 4; ++mt)
#pragma unroll
        for (int nt = 0; nt < 4; ++nt)
          acc[mt][nt] = MFMA16(af[mt], bfr[nt], acc[mt][nt]);
    }
    __syncthreads();
  }
#pragma unroll
  for (int mt = 0; mt < 4; ++mt) {
#pragma unroll
    for (int nt = 0; nt < 4; ++nt) {
      const int ncol = n0 + wn + nt * 16 + lr;
      const float bv = bias[ncol] * bias_scale;
      const int mbase = m0 + wm + mt * 16 + hi4 * 4;
#pragma unroll
      for (int r = 0; r < 4; ++r) {
        const int m = mbase + r;
        const float val = acc[mt][nt][r] + bv;
        if constexpr (MODE == 0) {
          ((u16*)Cout)[(size_t)m * N + ncol] = f2bf(val);
        } else {
          ((float*)Cout)[(size_t)m * N + ncol] = val + resid[(size_t)m * N + ncol];
        }
      }
    }
  }
}

// ---- 256x256 8-phase deep-pipelined GEMM (counted vmcnt) ----
template <int MODE>
__global__ __launch_bounds__(512, 2) void gemm256(const u16* __restrict__ A,
                                                  const u16* __restrict__ Bt,
                                                  const float* __restrict__ bias,
                                                  const float* __restrict__ bias2,
                                                  u16* __restrict__ Cout,
                                                  u16* __restrict__ Vout,
                                                  int M, int N, int K, int nmajor) {
  __shared__ __align__(16) u16 sA[2][2][256 * 32];
  __shared__ __align__(16) u16 sB[2][2][256 * 32];
  const int nbx = M >> 8, nby = N >> 8;
  const int nblk = nbx * nby;
  const int cpx = nblk >> 3;
  const int wg0 = blockIdx.x;
  const int wg = (wg0 & 7) * cpx + (wg0 >> 3);
  int mi, ni;
  if (nmajor) { ni = wg % nby; mi = wg / nby; } else { mi = wg % nbx; ni = wg / nbx; }
  const int m0 = mi << 8, n0 = ni << 8;
  const int tid = threadIdx.x;
  const int lane = tid & 63, wave = tid >> 6;
  const int wr = wave >> 2, wc = wave & 3;
  const int lr = lane & 15, hi4 = lane >> 4;
  const int rdoct = (hi4 ^ ((lr >> 1) & 3)) * 8;
  const int NT = K >> 6;

  auto stageA = [&](int t, int kh) {
#pragma unroll
    for (int i = 0; i < 2; ++i) {
      int idx = i * 512 + tid;
      int r = idx >> 2, go = (idx & 3) ^ ((r >> 1) & 3);
      GLDS16(A + (size_t)(m0 + r) * K + t * 64 + kh * 32 + go * 8,
             &sA[t & 1][kh][(i * 512 + wave * 64) * 8]);
    }
  };
  auto stageB = [&](int t, int kh) {
#pragma unroll
    for (int i = 0; i < 2; ++i) {
      int idx = i * 512 + tid;
      int r = idx >> 2, go = (idx & 3) ^ ((r >> 1) & 3);
      GLDS16(Bt + (size_t)(n0 + r) * K + t * 64 + kh * 32 + go * 8,
             &sB[t & 1][kh][(i * 512 + wave * 64) * 8]);
    }
  };

  f32x4 acc[8][4] = {};
  bf16x8 af[4], bf[4];

  stageA(0, 0); stageB(0, 0); stageA(0, 1); stageB(0, 1);
  asm volatile("s_waitcnt vmcnt(4)" ::: "memory");
  __builtin_amdgcn_s_barrier();
  __builtin_amdgcn_sched_barrier(0);

  for (int t = 0; t < NT; ++t) {
    const int buf = t & 1;
    const bool pre = (t + 1 < NT);
#pragma unroll
    for (int kh = 0; kh < 2; ++kh) {
#pragma unroll
      for (int nt = 0; nt < 4; ++nt)
        bf[nt] = __builtin_bit_cast(bf16x8,
            *(const s16x8*)&sB[buf][kh][(wc * 64 + nt * 16 + lr) * 32 + rdoct]);
#pragma unroll
      for (int mf = 0; mf < 4; ++mf)
        af[mf] = __builtin_bit_cast(bf16x8,
            *(const s16x8*)&sA[buf][kh][(wr * 128 + mf * 16 + lr) * 32 + rdoct]);
      if (pre) stageA(t + 1, kh);
      __builtin_amdgcn_s_barrier();
      asm volatile("s_waitcnt lgkmcnt(0)" ::: "memory");
      __builtin_amdgcn_sched_barrier(0);
      __builtin_amdgcn_s_setprio(1);
#pragma unroll
      for (int mf = 0; mf < 4; ++mf)
#pragma unroll
        for (int nt = 0; nt < 4; ++nt)
          acc[mf][nt] = MFMA16(af[mf], bf[nt], acc[mf][nt]);
      __builtin_amdgcn_s_setprio(0);
      __builtin_amdgcn_s_barrier();
      __builtin_amdgcn_sched_barrier(0);
#pragma unroll
      for (int mf = 0; mf < 4; ++mf)
        af[mf] = __builtin_bit_cast(bf16x8,
            *(const s16x8*)&sA[buf][kh][(wr * 128 + (4 + mf) * 16 + lr) * 32 + rdoct]);
      if (pre) stageB(t + 1, kh);
      __builtin_amdgcn_s_barrier();
      asm volatile("s_waitcnt lgkmcnt(0)" ::: "memory");
      __builtin_amdgcn_sched_barrier(0);
      __builtin_amdgcn_s_setprio(1);
#pragma unroll
      for (int mf = 0; mf < 4; ++mf)
#pragma unroll
        for (int nt = 0; nt < 4; ++nt)
          acc[4 + mf][nt] = MFMA16(af[mf], bf[nt], acc[4 + mf][nt]);
      __builtin_amdgcn_s_setprio(0);
      if (pre)
        asm volatile("s_waitcnt vmcnt(4)" ::: "memory");
      else
        asm volatile("s_waitcnt vmcnt(0)" ::: "memory");
      __builtin_amdgcn_s_barrier();
      __builtin_amdgcn_sched_barrier(0);
    }
  }

  if constexpr (MODE == 0) {
#pragma unroll
    for (int mf = 0; mf < 8; ++mf) {
#pragma unroll
      for (int nt = 0; nt < 4; ++nt) {
        const int ncol = n0 + wc * 64 + nt * 16 + lr;
        const int mbase = m0 + wr * 128 + mf * 16 + hi4 * 4;
        const bool isk = ncol < 1024;
        const int vc = isk ? ncol : ncol - 1024;
        const float bv = isk ? bias[ncol] : bias2[vc];
#pragma unroll
        for (int r = 0; r < 4; ++r) {
          const int m = mbase + r;
          const float val = acc[mf][nt][r] + bv;
          if (isk) {
            Cout[(size_t)m * 1024 + ncol] = f2bf(val);
          } else {
            size_t vidx = ((size_t)((m >> 12) * 1024 + vc) << 12) | (size_t)(m & 4095);
            Vout[vidx] = f2bf(val);
          }
        }
      }
    }
  } else {
#pragma unroll
    for (int mf = 0; mf < 8; ++mf) {
      const int mbase = m0 + wr * 128 + mf * 16 + hi4 * 4;
#pragma unroll
      for (int p = 0; p < 2; ++p) {
        const int oc = (((n0 + wc * 64 + p * 32) >> 5) << 4) + lr;
        const float ba = bias[oc];
        const float bg = bias[oc + 4096];
#pragma unroll
        for (int r = 0; r < 4; ++r) {
          const int m = mbase + r;
          float a = acc[mf][2 * p][r] + ba;
          float g = acc[mf][2 * p + 1][r] + bg;
          Cout[(size_t)m * 4096 + oc] = f2bf(a * gelu_t(g));
        }
      }
    }
  }
}

// ---- flash attention v5: grid 256 (1/CU), 4 waves x 64 q (2 q-groups/wave) ----
// K/V frag reads shared across q-groups (halves LDS read traffic); NQ_b=256 halves
// staging redundancy. 3-buffer LDS, 2-tile prefetch, counted vmcnt(4).
__global__ __launch_bounds__(256, 1) void flash_attn(const u16* __restrict__ Qg,
                                                     const u16* __restrict__ Kg,
                                                     const u16* __restrict__ Vt,
                                                     u16* __restrict__ Og) {
  __shared__ u16 Ks[3][64 * 64];
  __shared__ u16 Vs[3][64 * 64];
  const int id = blockIdx.x;  // 256 blocks = 8 qb x 32 bh
  const int rr = id & 31;
  const int bh = (rr & 7) * 4 + (rr >> 3);  // 4 bh per XCD -> 4MB K/V = L2-resident
  const int qb = id >> 5;                   // 0..7
  const int b = bh >> 4, h = bh & 15;
  const int q0 = qb * 256;
  const int tid = threadIdx.x;
  const int lane = tid & 63, wave = tid >> 6;
  const int lq = lane & 31, hi = lane >> 5;
  const u16* Kbase = Kg + (size_t)(b * 4096) * 1024 + h * 64;
  const u16* Vbase = Vt + (size_t)((b * 16 + h) * 64) * 4096;
  // Q fragments for both q-groups (g=0: rows +0..31, g=1: rows +32..63)
  bf16x8 qf0[4], qf1[4];
  const size_t qrow0 = (size_t)(b * 2048 + q0 + wave * 64 + lq);
  const size_t qrow1 = qrow0 + 32;
#pragma unroll
  for (int dc = 0; dc < 4; ++dc) {
    qf0[dc] = __builtin_bit_cast(bf16x8, *(const s16x8*)&Qg[qrow0 * 1024 + h * 64 + dc * 16 + hi * 8]);
    qf1[dc] = __builtin_bit_cast(bf16x8, *(const s16x8*)&Qg[qrow1 * 1024 + h * 64 + dc * 16 + hi * 8]);
  }
  f32x16 oacc00 = {}, oacc01 = {}, oacc10 = {}, oacc11 = {};
  float l0 = 0.0f, l1 = 0.0f;

  auto stage = [&](int buf, int tile) {  // 4 gload_lds per thread
    const int kv0 = tile * 64;
#pragma unroll
    for (int i = 0; i < 2; ++i) {
      int s = i * 256 + tid;
      int r = s >> 3;
      int inb = ((s & 7) * 16) ^ ((r & 7) << 4);
      GLDS16(Kbase + (size_t)(kv0 + r) * 1024 + (inb >> 1), &Ks[buf][(i * 256 + wave * 64) * 8]);
    }
#pragma unroll
    for (int i = 0; i < 2; ++i) {
      int s = i * 256 + tid;
      int r = s >> 3;
      int inb = ((s & 7) * 16) ^ ((r & 7) << 4);
      GLDS16(Vbase + (size_t)r * 4096 + kv0 + (inb >> 1), &Vs[buf][(i * 256 + wave * 64) * 8]);
    }
  };

  // softmax + pack one q-group: s values -> exp2 -> tree sum -> bf16 P^T frags
  auto softpack = [&](f32x16 sA, f32x16 sB, bf16x8* pf, float& lrun) {
#pragma unroll
    for (int i = 0; i < 16; ++i) sA[i] = __builtin_amdgcn_exp2f(sA[i]);
#pragma unroll
    for (int i = 0; i < 16; ++i) sB[i] = __builtin_amdgcn_exp2f(sB[i]);
    float a0 = (sA[0] + sA[1]) + (sA[2] + sA[3]);
    float a1 = (sA[4] + sA[5]) + (sA[6] + sA[7]);
    float a2 = (sA[8] + sA[9]) + (sA[10] + sA[11]);
    float a3 = (sA[12] + sA[13]) + (sA[14] + sA[15]);
    float b0 = (sB[0] + sB[1]) + (sB[2] + sB[3]);
    float b1 = (sB[4] + sB[5]) + (sB[6] + sB[7]);
    float b2 = (sB[8] + sB[9]) + (sB[10] + sB[11]);
    float b3 = (sB[12] + sB[13]) + (sB[14] + sB[15]);
    float ts = ((a0 + a1) + (a2 + a3)) + ((b0 + b1) + (b2 + b3));
    ts += __shfl_xor(ts, 32);
    lrun += ts;
    u32 wa[8], wb[8];
#pragma unroll
    for (int i = 0; i < 8; ++i) wa[i] = cvtpk(sA[2 * i], sA[2 * i + 1]);
#pragma unroll
    for (int i = 0; i < 8; ++i) wb[i] = cvtpk(sB[2 * i], sB[2 * i + 1]);
    u32 x0 = wa[0], y0 = wa[2];
    asm("v_permlane32_swap_b32 %0, %1" : "+v"(x0), "+v"(y0));
    u32 x1 = wa[1], y1 = wa[3];
    asm("v_permlane32_swap_b32 %0, %1" : "+v"(x1), "+v"(y1));
    u32 x2 = wa[4], y2 = wa[6];
    asm("v_permlane32_swap_b32 %0, %1" : "+v"(x2), "+v"(y2));
    u32 x3 = wa[5], y3 = wa[7];
    asm("v_permlane32_swap_b32 %0, %1" : "+v"(x3), "+v"(y3));
    u32 z0 = wb[0], u0 = wb[2];
    asm("v_permlane32_swap_b32 %0, %1" : "+v"(z0), "+v"(u0));
    u32 z1 = wb[1], u1 = wb[3];
    asm("v_permlane32_swap_b32 %0, %1" : "+v"(z1), "+v"(u1));
    u32 z2 = wb[4], u2 = wb[6];
    asm("v_permlane32_swap_b32 %0, %1" : "+v"(z2), "+v"(u2));
    u32 z3 = wb[5], u3 = wb[7];
    asm("v_permlane32_swap_b32 %0, %1" : "+v"(z3), "+v"(u3));
    u32x4 t00 = {x0, x1, y0, y1};
    u32x4 t01 = {x2, x3, y2, y3};
    u32x4 t10 = {z0, z1, u0, u1};
    u32x4 t11 = {z2, z3, u2, u3};
    pf[0] = __builtin_bit_cast(bf16x8, t00);
    pf[1] = __builtin_bit_cast(bf16x8, t01);
    pf[2] = __builtin_bit_cast(bf16x8, t10);
    pf[3] = __builtin_bit_cast(bf16x8, t11);
  };

  // prologue: stage tiles 0,1 (8 loads); wait tile 0 (4 oldest)
  stage(0, 0);
  stage(1, 1);
  asm volatile("s_waitcnt vmcnt(4)" ::: "memory");
  __builtin_amdgcn_s_barrier();
  __builtin_amdgcn_sched_barrier(0);

  for (int t = 0; t < 64; ++t) {
    const int buf = t % 3;
    if (t + 2 < 64) stage((t + 2) % 3, t + 2);
    // K fragments (8 reads, shared by both q-groups)
    bf16x8 kf[8];
#pragma unroll
    for (int st = 0; st < 2; ++st)
#pragma unroll
      for (int dc = 0; dc < 4; ++dc) {
        int row = st * 32 + lq;
        int inb = (dc * 32 + hi * 16) ^ ((row & 7) << 4);
        kf[st * 4 + dc] = __builtin_bit_cast(bf16x8, *(const s16x8*)&Ks[buf][row * 64 + (inb >> 1)]);
      }
    // QK^T group 0
    f32x16 sA = {}, sB = {};
    __builtin_amdgcn_s_setprio(1);
#pragma unroll
    for (int dc = 0; dc < 4; ++dc) sA = MFMA32(kf[dc], qf0[dc], sA);
#pragma unroll
    for (int dc = 0; dc < 4; ++dc) sB = MFMA32(kf[4 + dc], qf0[dc], sB);
    __builtin_amdgcn_s_setprio(0);
    bf16x8 pf0[4];
    softpack(sA, sB, pf0, l0);
    // QK^T group 1 (reuses kf)
    f32x16 tA = {}, tB = {};
    __builtin_amdgcn_s_setprio(1);
#pragma unroll
    for (int dc = 0; dc < 4; ++dc) tA = MFMA32(kf[dc], qf1[dc], tA);
#pragma unroll
    for (int dc = 0; dc < 4; ++dc) tB = MFMA32(kf[4 + dc], qf1[dc], tB);
    __builtin_amdgcn_s_setprio(0);
    bf16x8 pf1[4];
    softpack(tA, tB, pf1, l1);
    // PV: V fragments read once, used by both q-groups
    __builtin_amdgcn_s_setprio(1);
#pragma unroll
    for (int st = 0; st < 2; ++st)
#pragma unroll
      for (int c = 0; c < 2; ++c) {
        const int pi = st * 2 + c;
        int rowa = lq;
        int inba = (st * 64 + c * 32 + hi * 16) ^ ((rowa & 7) << 4);
        bf16x8 vfa = __builtin_bit_cast(bf16x8, *(const s16x8*)&Vs[buf][rowa * 64 + (inba >> 1)]);
        int rowb = 32 + lq;
        int inbb = (st * 64 + c * 32 + hi * 16) ^ ((rowb & 7) << 4);
        bf16x8 vfb = __builtin_bit_cast(bf16x8, *(const s16x8*)&Vs[buf][rowb * 64 + (inbb >> 1)]);
        oacc00 = MFMA32(vfa, pf0[pi], oacc00);
        oacc01 = MFMA32(vfb, pf0[pi], oacc01);
        oacc10 = MFMA32(vfa, pf1[pi], oacc10);
        oacc11 = MFMA32(vfb, pf1[pi], oacc11);
      }
    __builtin_amdgcn_s_setprio(0);
    if (t + 2 < 64)
      asm volatile("s_waitcnt vmcnt(4)" ::: "memory");
    else
      asm volatile("s_waitcnt vmcnt(0)" ::: "memory");
    __builtin_amdgcn_s_barrier();
    __builtin_amdgcn_sched_barrier(0);
  }
  const float r0v = 1.0f / l0, r1v = 1.0f / l1;
  u16* ob0 = Og + qrow0 * 1024 + h * 64;
  u16* ob1 = Og + qrow1 * 1024 + h * 64;
#pragma unroll
  for (int rp = 0; rp < 8; ++rp) {
    int r0 = rp * 2;
    int d0 = (r0 & 3) + 8 * (r0 >> 2) + 4 * hi;
    *(u32*)&ob0[d0] = cvtpk(oacc00[r0] * r0v, oacc00[r0 + 1] * r0v);
    *(u32*)&ob0[32 + d0] = cvtpk(oacc01[r0] * r0v, oacc01[r0 + 1] * r0v);
    *(u32*)&ob1[d0] = cvtpk(oacc10[r0] * r1v, oacc10[r0 + 1] * r1v);
    *(u32*)&ob1[32 + d0] = cvtpk(oacc11[r0] * r1v, oacc11[r0 + 1] * r1v);
  }
}

extern "C" void kernel_launch(void* const* d_in, const int* in_sizes, int n_in,
                              void* d_out, int out_size, void* d_ws, size_t ws_size,
                              hipStream_t stream) {
  (void)in_sizes; (void)n_in; (void)out_size; (void)ws_size;
  const float* inputs_q = (const float*)d_in[0];
  const float* inputs_kv = (const float*)d_in[1];
  const float* ln_q_scale = (const float*)d_in[2];
  const float* ln_q_bias = (const float*)d_in[3];
  const float* ln_kv_scale = (const float*)d_in[4];
  const float* ln_kv_bias = (const float*)d_in[5];
  const float* Wq = (const float*)d_in[6];
  const float* bq = (const float*)d_in[7];
  const float* Wk = (const float*)d_in[8];
  const float* bk = (const float*)d_in[9];
  const float* Wv = (const float*)d_in[10];
  const float* bv = (const float*)d_in[11];
  const float* Wo = (const float*)d_in[12];
  const float* bo = (const float*)d_in[13];
  const float* ln2_scale = (const float*)d_in[14];
  const float* ln2_bias = (const float*)d_in[15];
  const float* W1 = (const float*)d_in[16];
  const float* b1 = (const float*)d_in[17];
  const float* W2 = (const float*)d_in[18];
  const float* b2 = (const float*)d_in[19];
  float* out = (float*)d_out;
  char* ws = (char*)d_ws;
  const size_t MB = 1ull << 20;
  u16* lnq = (u16*)(ws + 0);
  u16* lnkv = (u16*)(ws + 8 * MB);
  u16* Qb = (u16*)(ws + 24 * MB);
  u16* Kb = (u16*)(ws + 32 * MB);
  u16* Vtb = (u16*)(ws + 48 * MB);
  u16* Ob = (u16*)(ws + 64 * MB);
  float* xbuf = (float*)(ws + 72 * MB);
  u16* ln2b = (u16*)(ws + 88 * MB);
  u16* gg = (u16*)(ws + 96 * MB);
  u16* wqt = (u16*)(ws + 128 * MB);
  u16* wkvt = (u16*)(ws + 130 * MB);
  u16* wot = (u16*)(ws + 134 * MB);
  u16* w1i = (u16*)(ws + 136 * MB);
  u16* w2t = (u16*)(ws + 152 * MB);

  const float QSC = 0.125f * 1.44269504088896f;
  dim3 blk(256);
  prep_weights<<<dim3(4096), blk, 0, stream>>>(Wq, Wk, Wv, Wo, W1, W2, wqt, wkvt, wot, w1i, w2t, QSC);
  ln_fused<<<dim3(12288), blk, 0, stream>>>(inputs_q, inputs_kv, ln_q_scale, ln_q_bias,
                                            ln_kv_scale, ln_kv_bias, lnq, lnkv);
  gemm_nt<0><<<dim3(32, 8), blk, 0, stream>>>(lnq, wqt, bq, nullptr, Qb, 4096, 1024, 1024, QSC);
  gemm256<0><<<dim3(256), dim3(512), 0, stream>>>(lnkv, wkvt, bk, bv, Kb, Vtb, 8192, 2048, 1024, 1);
  flash_attn<<<dim3(256), blk, 0, stream>>>(Qb, Kb, Vtb, Ob);
  gemm_nt<2><<<dim3(32, 8), blk, 0, stream>>>(Ob, wot, bo, inputs_q, xbuf, 4096, 1024, 1024, 1.0f);
  ln_fused<<<dim3(4096), blk, 0, stream>>>(xbuf, xbuf, ln2_scale, ln2_bias, ln2_scale, ln2_bias,
                                           ln2b, ln2b);
  gemm256<1><<<dim3(512), dim3(512), 0, stream>>>(ln2b, w1i, b1, nullptr, gg, nullptr, 4096, 8192, 1024, 0);
  gemm_nt<2><<<dim3(32, 8), blk, 0, stream>>>(gg, w2t, b2, xbuf, out, 4096, 1024, 4096, 1.0f);
}

// Round 10
// 388.401 us; speedup vs baseline: 1.0790x; 1.0790x over previous
//
#include <hip/hip_runtime.h>

typedef unsigned short u16;
typedef unsigned int u32;
typedef float f32x4 __attribute__((ext_vector_type(4)));
typedef float f32x16 __attribute__((ext_vector_type(16)));
typedef __bf16 bf16x8 __attribute__((ext_vector_type(8)));
typedef short s16x8 __attribute__((ext_vector_type(8)));
typedef short s16x4 __attribute__((ext_vector_type(4)));
typedef u32 u32x4 __attribute__((ext_vector_type(4)));

#define MFMA16(a, b, c) __builtin_amdgcn_mfma_f32_16x16x32_bf16((a), (b), (c), 0, 0, 0)
#define MFMA32(a, b, c) __builtin_amdgcn_mfma_f32_32x32x16_bf16((a), (b), (c), 0, 0, 0)

typedef const __attribute__((address_space(1))) void* gas1_t;
typedef __attribute__((address_space(3))) void* las3_t;
#define GLDS16(g, l) __builtin_amdgcn_global_load_lds((gas1_t)(g), (las3_t)(l), 16, 0, 0)

static __device__ __forceinline__ u16 f2bf(float f) {
  u32 u = __builtin_bit_cast(u32, f);
  u += 0x7FFFu + ((u >> 16) & 1u);
  return (u16)(u >> 16);
}
static __device__ __forceinline__ u32 cvtpk(float lo, float hi) {
  u32 r;
  asm("v_cvt_pk_bf16_f32 %0, %1, %2" : "=v"(r) : "v"(lo), "v"(hi));
  return r;
}
static __device__ __forceinline__ float gelu_t(float g) {
  float u = 0.7978845608f * (g + 0.044715f * g * g * g);
  float e = __expf(2.0f * u);
  float t = 1.0f - 2.0f / (e + 1.0f);
  return 0.5f * g * (1.0f + t);
}

// ---- ALL weight preprocessing in one launch (4096 blocks) ----
__global__ __launch_bounds__(256) void prep_weights(const float* __restrict__ Wq,
                                                    const float* __restrict__ Wk,
                                                    const float* __restrict__ Wv,
                                                    const float* __restrict__ Wo,
                                                    const float* __restrict__ W1,
                                                    const float* __restrict__ W2,
                                                    u16* __restrict__ wqt,
                                                    u16* __restrict__ wkvt,
                                                    u16* __restrict__ wot,
                                                    u16* __restrict__ w1i,
                                                    u16* __restrict__ w2t, float qsc) {
  __shared__ u16 t[64][72];
  const int id = blockIdx.x;
  const int tid = threadIdx.x;
  auto tileT = [&](const float* in, u16* out, int K, int N, int k0, int n0, float scale) {
#pragma unroll
    for (int i = 0; i < 16; ++i) {
      int idx = tid + i * 256;
      int r = idx >> 6, c = idx & 63;
      t[r][c] = f2bf(in[(size_t)(k0 + r) * N + n0 + c] * scale);
    }
    __syncthreads();
#pragma unroll
    for (int i = 0; i < 16; ++i) {
      int idx = tid + i * 256;
      int r = idx >> 6, c = idx & 63;
      out[(size_t)(n0 + r) * K + k0 + c] = t[c][r];
    }
  };
  if (id < 256) {
    tileT(Wq, wqt, 1024, 1024, (id & 15) * 64, (id >> 4) * 64, qsc);
  } else if (id < 512) {
    int i2 = id - 256;
    tileT(Wk, wkvt, 1024, 1024, (i2 & 15) * 64, (i2 >> 4) * 64, 1.0f);
  } else if (id < 768) {
    int i2 = id - 512;
    tileT(Wv, wkvt + 1024 * 1024, 1024, 1024, (i2 & 15) * 64, (i2 >> 4) * 64, 1.0f);
  } else if (id < 1024) {
    int i2 = id - 768;
    tileT(Wo, wot, 1024, 1024, (i2 & 15) * 64, (i2 >> 4) * 64, 1.0f);
  } else if (id < 3072) {
    int i2 = id - 1024;
    int k0 = (i2 & 15) * 64, n0 = (i2 >> 4) * 64;
#pragma unroll
    for (int i = 0; i < 16; ++i) {
      int idx = tid + i * 256;
      int r = idx >> 6, c = idx & 63;
      int np = n0 + c;
      int orig = ((np >> 5) << 4) + (np & 15) + (((np >> 4) & 1) << 12);
      t[r][c] = f2bf(W1[(size_t)(k0 + r) * 8192 + orig]);
    }
    __syncthreads();
#pragma unroll
    for (int i = 0; i < 16; ++i) {
      int idx = tid + i * 256;
      int r = idx >> 6, c = idx & 63;
      w1i[(size_t)(n0 + r) * 1024 + k0 + c] = t[c][r];
    }
  } else {
    int i3 = id - 3072;
    tileT(W2, w2t, 4096, 1024, (i3 & 63) * 64, (i3 >> 6) * 64, 1.0f);
  }
}

// ---- fused LayerNorm: blocks 0..4095 = q rows; 4096..12287 = kv rows ----
__global__ __launch_bounds__(256) void ln_fused(const float* __restrict__ xq,
                                                const float* __restrict__ xkv,
                                                const float* __restrict__ scq,
                                                const float* __restrict__ biq,
                                                const float* __restrict__ sckv,
                                                const float* __restrict__ bikv,
                                                u16* __restrict__ outq,
                                                u16* __restrict__ outkv) {
  const int id = blockIdx.x;
  const bool isq = id < 4096;
  const int row = isq ? id : id - 4096;
  const float* x = isq ? xq : xkv;
  const float* sc = isq ? scq : sckv;
  const float* bi = isq ? biq : bikv;
  u16* out = isq ? outq : outkv;
  int tid = threadIdx.x;
  float4 v = ((const float4*)(x + (size_t)row * 1024))[tid];
  float s = v.x + v.y + v.z + v.w;
  float s2 = v.x * v.x + v.y * v.y + v.z * v.z + v.w * v.w;
  for (int m = 1; m < 64; m <<= 1) {
    s += __shfl_xor(s, m);
    s2 += __shfl_xor(s2, m);
  }
  __shared__ float rs[4], rs2[4];
  int wave = tid >> 6, lane = tid & 63;
  if (lane == 0) { rs[wave] = s; rs2[wave] = s2; }
  __syncthreads();
  s = rs[0] + rs[1] + rs[2] + rs[3];
  s2 = rs2[0] + rs2[1] + rs2[2] + rs2[3];
  float mu = s * (1.0f / 1024.0f);
  float var = s2 * (1.0f / 1024.0f) - mu * mu;
  float inv = rsqrtf(var + 1e-6f);
  float4 scv = ((const float4*)sc)[tid];
  float4 biv = ((const float4*)bi)[tid];
  s16x4 o;
  o[0] = (short)f2bf((v.x - mu) * inv * scv.x + biv.x);
  o[1] = (short)f2bf((v.y - mu) * inv * scv.y + biv.y);
  o[2] = (short)f2bf((v.z - mu) * inv * scv.z + biv.z);
  o[3] = (short)f2bf((v.w - mu) * inv * scv.w + biv.w);
  *(s16x4*)(out + (size_t)row * 1024 + tid * 4) = o;
}

// ---- 128x128 GEMM (2-phase, swizzled, 0 conflicts) ----
template <int MODE>
__global__ __launch_bounds__(256) void gemm_nt(const u16* __restrict__ A,
                                               const u16* __restrict__ Bt,
                                               const float* __restrict__ bias,
                                               const float* __restrict__ resid,
                                               void* __restrict__ Cout,
                                               int M, int N, int K, float bias_scale) {
  __shared__ u16 As[128 * 64];
  __shared__ u16 Bs[128 * 64];
  const int nbx = gridDim.x;
  const int nwg = nbx * gridDim.y;
  const int wg0 = blockIdx.y * nbx + blockIdx.x;
  const int wg = (nwg & 7) ? wg0 : (wg0 & 7) * (nwg >> 3) + (wg0 >> 3);
  const int m0 = (wg % nbx) * 128, n0 = (wg / nbx) * 128;
  const int tid = threadIdx.x;
  const int lane = tid & 63, wave = tid >> 6;
  const int wm = (wave >> 1) * 64, wn = (wave & 1) * 64;
  const int lr = lane & 15, hi4 = lane >> 4;
  f32x4 acc[4][4] = {};
  for (int k0 = 0; k0 < K; k0 += 64) {
#pragma unroll
    for (int i = 0; i < 4; ++i) {
      int s = i * 256 + tid;
      int r = s >> 3, slot = s & 7;
      int gslot = slot ^ (r & 7);
      int ldst = (i * 256 + wave * 64) * 8;
      GLDS16(A + (size_t)(m0 + r) * K + k0 + gslot * 8, &As[ldst]);
      GLDS16(Bt + (size_t)(n0 + r) * K + k0 + gslot * 8, &Bs[ldst]);
    }
    __syncthreads();
#pragma unroll
    for (int ks = 0; ks < 2; ++ks) {
      const int sl = ((ks * 4 + hi4) ^ (lr & 7)) * 8;
      bf16x8 af[4], bfr[4];
#pragma unroll
      for (int t = 0; t < 4; ++t) {
        af[t] = __builtin_bit_cast(bf16x8, *(const s16x8*)&As[(wm + t * 16 + lr) * 64 + sl]);
        bfr[t] = __builtin_bit_cast(bf16x8, *(const s16x8*)&Bs[(wn + t * 16 + lr) * 64 + sl]);
      }
#pragma unroll
      for (int mt = 0; mt < 4; ++mt)
#pragma unroll
        for (int nt = 0; nt < 4; ++nt)
          acc[mt][nt] = MFMA16(af[mt], bfr[nt], acc[mt][nt]);
    }
    __syncthreads();
  }
#pragma unroll
  for (int mt = 0; mt < 4; ++mt) {
#pragma unroll
    for (int nt = 0; nt < 4; ++nt) {
      const int ncol = n0 + wn + nt * 16 + lr;
      const float bv = bias[ncol] * bias_scale;
      const int mbase = m0 + wm + mt * 16 + hi4 * 4;
#pragma unroll
      for (int r = 0; r < 4; ++r) {
        const int m = mbase + r;
        const float val = acc[mt][nt][r] + bv;
        if constexpr (MODE == 0) {
          ((u16*)Cout)[(size_t)m * N + ncol] = f2bf(val);
        } else {
          ((float*)Cout)[(size_t)m * N + ncol] = val + resid[(size_t)m * N + ncol];
        }
      }
    }
  }
}

// ---- 256x256 8-phase deep-pipelined GEMM (counted vmcnt) ----
template <int MODE>
__global__ __launch_bounds__(512, 2) void gemm256(const u16* __restrict__ A,
                                                  const u16* __restrict__ Bt,
                                                  const float* __restrict__ bias,
                                                  const float* __restrict__ bias2,
                                                  u16* __restrict__ Cout,
                                                  u16* __restrict__ Vout,
                                                  int M, int N, int K, int nmajor) {
  __shared__ __align__(16) u16 sA[2][2][256 * 32];
  __shared__ __align__(16) u16 sB[2][2][256 * 32];
  const int nbx = M >> 8, nby = N >> 8;
  const int nblk = nbx * nby;
  const int cpx = nblk >> 3;
  const int wg0 = blockIdx.x;
  const int wg = (wg0 & 7) * cpx + (wg0 >> 3);
  int mi, ni;
  if (nmajor) { ni = wg % nby; mi = wg / nby; } else { mi = wg % nbx; ni = wg / nbx; }
  const int m0 = mi << 8, n0 = ni << 8;
  const int tid = threadIdx.x;
  const int lane = tid & 63, wave = tid >> 6;
  const int wr = wave >> 2, wc = wave & 3;
  const int lr = lane & 15, hi4 = lane >> 4;
  const int rdoct = (hi4 ^ ((lr >> 1) & 3)) * 8;
  const int NT = K >> 6;

  auto stageA = [&](int t, int kh) {
#pragma unroll
    for (int i = 0; i < 2; ++i) {
      int idx = i * 512 + tid;
      int r = idx >> 2, go = (idx & 3) ^ ((r >> 1) & 3);
      GLDS16(A + (size_t)(m0 + r) * K + t * 64 + kh * 32 + go * 8,
             &sA[t & 1][kh][(i * 512 + wave * 64) * 8]);
    }
  };
  auto stageB = [&](int t, int kh) {
#pragma unroll
    for (int i = 0; i < 2; ++i) {
      int idx = i * 512 + tid;
      int r = idx >> 2, go = (idx & 3) ^ ((r >> 1) & 3);
      GLDS16(Bt + (size_t)(n0 + r) * K + t * 64 + kh * 32 + go * 8,
             &sB[t & 1][kh][(i * 512 + wave * 64) * 8]);
    }
  };

  f32x4 acc[8][4] = {};
  bf16x8 af[4], bf[4];

  stageA(0, 0); stageB(0, 0); stageA(0, 1); stageB(0, 1);
  asm volatile("s_waitcnt vmcnt(4)" ::: "memory");
  __builtin_amdgcn_s_barrier();
  __builtin_amdgcn_sched_barrier(0);

  for (int t = 0; t < NT; ++t) {
    const int buf = t & 1;
    const bool pre = (t + 1 < NT);
#pragma unroll
    for (int kh = 0; kh < 2; ++kh) {
#pragma unroll
      for (int nt = 0; nt < 4; ++nt)
        bf[nt] = __builtin_bit_cast(bf16x8,
            *(const s16x8*)&sB[buf][kh][(wc * 64 + nt * 16 + lr) * 32 + rdoct]);
#pragma unroll
      for (int mf = 0; mf < 4; ++mf)
        af[mf] = __builtin_bit_cast(bf16x8,
            *(const s16x8*)&sA[buf][kh][(wr * 128 + mf * 16 + lr) * 32 + rdoct]);
      if (pre) stageA(t + 1, kh);
      __builtin_amdgcn_s_barrier();
      asm volatile("s_waitcnt lgkmcnt(0)" ::: "memory");
      __builtin_amdgcn_sched_barrier(0);
      __builtin_amdgcn_s_setprio(1);
#pragma unroll
      for (int mf = 0; mf < 4; ++mf)
#pragma unroll
        for (int nt = 0; nt < 4; ++nt)
          acc[mf][nt] = MFMA16(af[mf], bf[nt], acc[mf][nt]);
      __builtin_amdgcn_s_setprio(0);
      __builtin_amdgcn_s_barrier();
      __builtin_amdgcn_sched_barrier(0);
#pragma unroll
      for (int mf = 0; mf < 4; ++mf)
        af[mf] = __builtin_bit_cast(bf16x8,
            *(const s16x8*)&sA[buf][kh][(wr * 128 + (4 + mf) * 16 + lr) * 32 + rdoct]);
      if (pre) stageB(t + 1, kh);
      __builtin_amdgcn_s_barrier();
      asm volatile("s_waitcnt lgkmcnt(0)" ::: "memory");
      __builtin_amdgcn_sched_barrier(0);
      __builtin_amdgcn_s_setprio(1);
#pragma unroll
      for (int mf = 0; mf < 4; ++mf)
#pragma unroll
        for (int nt = 0; nt < 4; ++nt)
          acc[4 + mf][nt] = MFMA16(af[mf], bf[nt], acc[4 + mf][nt]);
      __builtin_amdgcn_s_setprio(0);
      if (pre)
        asm volatile("s_waitcnt vmcnt(4)" ::: "memory");
      else
        asm volatile("s_waitcnt vmcnt(0)" ::: "memory");
      __builtin_amdgcn_s_barrier();
      __builtin_amdgcn_sched_barrier(0);
    }
  }

  if constexpr (MODE == 0) {
#pragma unroll
    for (int mf = 0; mf < 8; ++mf) {
#pragma unroll
      for (int nt = 0; nt < 4; ++nt) {
        const int ncol = n0 + wc * 64 + nt * 16 + lr;
        const int mbase = m0 + wr * 128 + mf * 16 + hi4 * 4;
        const bool isk = ncol < 1024;
        const int vc = isk ? ncol : ncol - 1024;
        const float bv = isk ? bias[ncol] : bias2[vc];
#pragma unroll
        for (int r = 0; r < 4; ++r) {
          const int m = mbase + r;
          const float val = acc[mf][nt][r] + bv;
          if (isk) {
            Cout[(size_t)m * 1024 + ncol] = f2bf(val);
          } else {
            size_t vidx = ((size_t)((m >> 12) * 1024 + vc) << 12) | (size_t)(m & 4095);
            Vout[vidx] = f2bf(val);
          }
        }
      }
    }
  } else {
#pragma unroll
    for (int mf = 0; mf < 8; ++mf) {
      const int mbase = m0 + wr * 128 + mf * 16 + hi4 * 4;
#pragma unroll
      for (int p = 0; p < 2; ++p) {
        const int oc = (((n0 + wc * 64 + p * 32) >> 5) << 4) + lr;
        const float ba = bias[oc];
        const float bg = bias[oc + 4096];
#pragma unroll
        for (int r = 0; r < 4; ++r) {
          const int m = mbase + r;
          float a = acc[mf][2 * p][r] + ba;
          float g = acc[mf][2 * p + 1][r] + bg;
          Cout[(size_t)m * 4096 + oc] = f2bf(a * gelu_t(g));
        }
      }
    }
  }
}

// ---- flash attention (r4-proven best, 88.7us): 4 waves x 32 q, grid 512,
// K+V dbuf LDS, static softmax (serial sum), setprio ----
__global__ __launch_bounds__(256, 2) void flash_attn(const u16* __restrict__ Qg,
                                                     const u16* __restrict__ Kg,
                                                     const u16* __restrict__ Vt,
                                                     u16* __restrict__ Og) {
  __shared__ u16 Ks[2][64 * 64];
  __shared__ u16 Vs[2][64 * 64];
  const int id = blockIdx.x;
  const int bh = (id & 7) * 4 + ((id >> 3) & 3);
  const int qb = id >> 5;
  const int b = bh >> 4, h = bh & 15;
  const int q0 = qb * 128;
  const int tid = threadIdx.x;
  const int lane = tid & 63, wave = tid >> 6;
  const int lq = lane & 31, hi = lane >> 5;
  const u16* Kbase = Kg + (size_t)(b * 4096) * 1024 + h * 64;
  const u16* Vbase = Vt + (size_t)((b * 16 + h) * 64) * 4096;
  bf16x8 qf[4];
  const size_t qrow = (size_t)(b * 2048 + q0 + wave * 32 + lq);
#pragma unroll
  for (int dc = 0; dc < 4; ++dc)
    qf[dc] = __builtin_bit_cast(bf16x8, *(const s16x8*)&Qg[qrow * 1024 + h * 64 + dc * 16 + hi * 8]);

  f32x16 oacc0 = {}, oacc1 = {};
  float lrun = 0.0f;

  auto stage = [&](int buf, int tile) {
    const int kv0 = tile * 64;
#pragma unroll
    for (int i = 0; i < 2; ++i) {
      int s = i * 256 + tid;
      int r = s >> 3;
      int inb = ((s & 7) * 16) ^ ((r & 7) << 4);
      GLDS16(Kbase + (size_t)(kv0 + r) * 1024 + (inb >> 1), &Ks[buf][(i * 256 + wave * 64) * 8]);
    }
#pragma unroll
    for (int i = 0; i < 2; ++i) {
      int s = i * 256 + tid;
      int r = s >> 3;
      int inb = ((s & 7) * 16) ^ ((r & 7) << 4);
      GLDS16(Vbase + (size_t)r * 4096 + kv0 + (inb >> 1), &Vs[buf][(i * 256 + wave * 64) * 8]);
    }
  };

  stage(0, 0);
  __syncthreads();
  int cur = 0;
  for (int t = 0; t < 64; ++t) {
    if (t < 63) stage(cur ^ 1, t + 1);
    f32x16 sA = {}, sB = {};
    __builtin_amdgcn_s_setprio(1);
#pragma unroll
    for (int dc = 0; dc < 4; ++dc) {
      int row = lq;
      int inb = (dc * 32 + hi * 16) ^ ((row & 7) << 4);
      bf16x8 kf = __builtin_bit_cast(bf16x8, *(const s16x8*)&Ks[cur][row * 64 + (inb >> 1)]);
      sA = MFMA32(kf, qf[dc], sA);
    }
#pragma unroll
    for (int dc = 0; dc < 4; ++dc) {
      int row = 32 + lq;
      int inb = (dc * 32 + hi * 16) ^ ((row & 7) << 4);
      bf16x8 kf = __builtin_bit_cast(bf16x8, *(const s16x8*)&Ks[cur][row * 64 + (inb >> 1)]);
      sB = MFMA32(kf, qf[dc], sB);
    }
    __builtin_amdgcn_s_setprio(0);
    float ts = 0.0f;
#pragma unroll
    for (int i = 0; i < 16; ++i) {
      float p = __builtin_amdgcn_exp2f(sA[i]);
      sA[i] = p;
      ts += p;
    }
#pragma unroll
    for (int i = 0; i < 16; ++i) {
      float p = __builtin_amdgcn_exp2f(sB[i]);
      sB[i] = p;
      ts += p;
    }
    ts += __shfl_xor(ts, 32);
    lrun += ts;
    u32 wa[8], wb[8];
#pragma unroll
    for (int i = 0; i < 8; ++i) wa[i] = cvtpk(sA[2 * i], sA[2 * i + 1]);
#pragma unroll
    for (int i = 0; i < 8; ++i) wb[i] = cvtpk(sB[2 * i], sB[2 * i + 1]);
    u32 a0 = wa[0], c0 = wa[2];
    asm("v_permlane32_swap_b32 %0, %1" : "+v"(a0), "+v"(c0));
    u32 a1 = wa[1], c1 = wa[3];
    asm("v_permlane32_swap_b32 %0, %1" : "+v"(a1), "+v"(c1));
    u32 a2 = wa[4], c2 = wa[6];
    asm("v_permlane32_swap_b32 %0, %1" : "+v"(a2), "+v"(c2));
    u32 a3 = wa[5], c3 = wa[7];
    asm("v_permlane32_swap_b32 %0, %1" : "+v"(a3), "+v"(c3));
    u32 e0 = wb[0], g0 = wb[2];
    asm("v_permlane32_swap_b32 %0, %1" : "+v"(e0), "+v"(g0));
    u32 e1 = wb[1], g1 = wb[3];
    asm("v_permlane32_swap_b32 %0, %1" : "+v"(e1), "+v"(g1));
    u32 e2 = wb[4], g2 = wb[6];
    asm("v_permlane32_swap_b32 %0, %1" : "+v"(e2), "+v"(g2));
    u32 e3 = wb[5], g3 = wb[7];
    asm("v_permlane32_swap_b32 %0, %1" : "+v"(e3), "+v"(g3));
    u32x4 t00 = {a0, a1, c0, c1};
    u32x4 t01 = {a2, a3, c2, c3};
    u32x4 t10 = {e0, e1, g0, g1};
    u32x4 t11 = {e2, e3, g2, g3};
    bf16x8 p00 = __builtin_bit_cast(bf16x8, t00);
    bf16x8 p01 = __builtin_bit_cast(bf16x8, t01);
    bf16x8 p10 = __builtin_bit_cast(bf16x8, t10);
    bf16x8 p11 = __builtin_bit_cast(bf16x8, t11);
    __builtin_amdgcn_s_setprio(1);
#pragma unroll
    for (int st = 0; st < 2; ++st) {
      bf16x8 pc0 = st ? p10 : p00;
      bf16x8 pc1 = st ? p11 : p01;
#pragma unroll
      for (int c = 0; c < 2; ++c) {
        bf16x8 pf = c ? pc1 : pc0;
        {
          int row = lq;
          int inb = (st * 64 + c * 32 + hi * 16) ^ ((row & 7) << 4);
          bf16x8 vf = __builtin_bit_cast(bf16x8, *(const s16x8*)&Vs[cur][row * 64 + (inb >> 1)]);
          oacc0 = MFMA32(vf, pf, oacc0);
        }
        {
          int row = 32 + lq;
          int inb = (st * 64 + c * 32 + hi * 16) ^ ((row & 7) << 4);
          bf16x8 vf = __builtin_bit_cast(bf16x8, *(const s16x8*)&Vs[cur][row * 64 + (inb >> 1)]);
          oacc1 = MFMA32(vf, pf, oacc1);
        }
      }
    }
    __builtin_amdgcn_s_setprio(0);
    __syncthreads();
    cur ^= 1;
  }
  float rinv = 1.0f / lrun;
  u16* obase = Og + qrow * 1024 + h * 64;
#pragma unroll
  for (int rp = 0; rp < 8; ++rp) {
    int r0 = rp * 2;
    int d0 = (r0 & 3) + 8 * (r0 >> 2) + 4 * hi;
    *(u32*)&obase[d0] = cvtpk(oacc0[r0] * rinv, oacc0[r0 + 1] * rinv);
    *(u32*)&obase[32 + d0] = cvtpk(oacc1[r0] * rinv, oacc1[r0 + 1] * rinv);
  }
}

extern "C" void kernel_launch(void* const* d_in, const int* in_sizes, int n_in,
                              void* d_out, int out_size, void* d_ws, size_t ws_size,
                              hipStream_t stream) {
  (void)in_sizes; (void)n_in; (void)out_size; (void)ws_size;
  const float* inputs_q = (const float*)d_in[0];
  const float* inputs_kv = (const float*)d_in[1];
  const float* ln_q_scale = (const float*)d_in[2];
  const float* ln_q_bias = (const float*)d_in[3];
  const float* ln_kv_scale = (const float*)d_in[4];
  const float* ln_kv_bias = (const float*)d_in[5];
  const float* Wq = (const float*)d_in[6];
  const float* bq = (const float*)d_in[7];
  const float* Wk = (const float*)d_in[8];
  const float* bk = (const float*)d_in[9];
  const float* Wv = (const float*)d_in[10];
  const float* bv = (const float*)d_in[11];
  const float* Wo = (const float*)d_in[12];
  const float* bo = (const float*)d_in[13];
  const float* ln2_scale = (const float*)d_in[14];
  const float* ln2_bias = (const float*)d_in[15];
  const float* W1 = (const float*)d_in[16];
  const float* b1 = (const float*)d_in[17];
  const float* W2 = (const float*)d_in[18];
  const float* b2 = (const float*)d_in[19];
  float* out = (float*)d_out;
  char* ws = (char*)d_ws;
  const size_t MB = 1ull << 20;
  u16* lnq = (u16*)(ws + 0);
  u16* lnkv = (u16*)(ws + 8 * MB);
  u16* Qb = (u16*)(ws + 24 * MB);
  u16* Kb = (u16*)(ws + 32 * MB);
  u16* Vtb = (u16*)(ws + 48 * MB);
  u16* Ob = (u16*)(ws + 64 * MB);
  float* xbuf = (float*)(ws + 72 * MB);
  u16* ln2b = (u16*)(ws + 88 * MB);
  u16* gg = (u16*)(ws + 96 * MB);
  u16* wqt = (u16*)(ws + 128 * MB);
  u16* wkvt = (u16*)(ws + 130 * MB);
  u16* wot = (u16*)(ws + 134 * MB);
  u16* w1i = (u16*)(ws + 136 * MB);
  u16* w2t = (u16*)(ws + 152 * MB);

  const float QSC = 0.125f * 1.44269504088896f;
  dim3 blk(256);
  prep_weights<<<dim3(4096), blk, 0, stream>>>(Wq, Wk, Wv, Wo, W1, W2, wqt, wkvt, wot, w1i, w2t, QSC);
  ln_fused<<<dim3(12288), blk, 0, stream>>>(inputs_q, inputs_kv, ln_q_scale, ln_q_bias,
                                            ln_kv_scale, ln_kv_bias, lnq, lnkv);
  gemm_nt<0><<<dim3(32, 8), blk, 0, stream>>>(lnq, wqt, bq, nullptr, Qb, 4096, 1024, 1024, QSC);
  gemm256<0><<<dim3(256), dim3(512), 0, stream>>>(lnkv, wkvt, bk, bv, Kb, Vtb, 8192, 2048, 1024, 1);
  flash_attn<<<dim3(512), blk, 0, stream>>>(Qb, Kb, Vtb, Ob);
  gemm_nt<2><<<dim3(32, 8), blk, 0, stream>>>(Ob, wot, bo, inputs_q, xbuf, 4096, 1024, 1024, 1.0f);
  ln_fused<<<dim3(4096), blk, 0, stream>>>(xbuf, xbuf, ln2_scale, ln2_bias, ln2_scale, ln2_bias,
                                           ln2b, ln2b);
  gemm256<1><<<dim3(512), dim3(512), 0, stream>>>(ln2b, w1i, b1, nullptr, gg, nullptr, 4096, 8192, 1024, 0);
  gemm_nt<2><<<dim3(32, 8), blk, 0, stream>>>(gg, w2t, b2, xbuf, out, 4096, 1024, 4096, 1.0f);
}

// Round 11
// 376.712 us; speedup vs baseline: 1.1124x; 1.0310x over previous
//
#include <hip/hip_runtime.h>

typedef unsigned short u16;
typedef unsigned int u32;
typedef float f32x4 __attribute__((ext_vector_type(4)));
typedef float f32x16 __attribute__((ext_vector_type(16)));
typedef __bf16 bf16x8 __attribute__((ext_vector_type(8)));
typedef short s16x8 __attribute__((ext_vector_type(8)));
typedef short s16x4 __attribute__((ext_vector_type(4)));
typedef u32 u32x4 __attribute__((ext_vector_type(4)));

#define MFMA16(a, b, c) __builtin_amdgcn_mfma_f32_16x16x32_bf16((a), (b), (c), 0, 0, 0)
#define MFMA32(a, b, c) __builtin_amdgcn_mfma_f32_32x32x16_bf16((a), (b), (c), 0, 0, 0)

typedef const __attribute__((address_space(1))) void* gas1_t;
typedef __attribute__((address_space(3))) void* las3_t;
#define GLDS16(g, l) __builtin_amdgcn_global_load_lds((gas1_t)(g), (las3_t)(l), 16, 0, 0)

static __device__ __forceinline__ u16 f2bf(float f) {
  u32 u = __builtin_bit_cast(u32, f);
  u += 0x7FFFu + ((u >> 16) & 1u);
  return (u16)(u >> 16);
}
static __device__ __forceinline__ u32 cvtpk(float lo, float hi) {
  u32 r;
  asm("v_cvt_pk_bf16_f32 %0, %1, %2" : "=v"(r) : "v"(lo), "v"(hi));
  return r;
}
static __device__ __forceinline__ float gelu_t(float g) {
  float u = 0.7978845608f * (g + 0.044715f * g * g * g);
  float e = __expf(2.0f * u);
  float t = 1.0f - 2.0f / (e + 1.0f);
  return 0.5f * g * (1.0f + t);
}

// ---- ALL weight preprocessing + input LayerNorms in ONE launch (16384 blocks) ----
// id<4096: weight transposes (as before). id in [4096,8192): LN q row. [8192,16384): LN kv row.
__global__ __launch_bounds__(256) void prep_all(const float* __restrict__ Wq,
                                                const float* __restrict__ Wk,
                                                const float* __restrict__ Wv,
                                                const float* __restrict__ Wo,
                                                const float* __restrict__ W1,
                                                const float* __restrict__ W2,
                                                u16* __restrict__ wqt,
                                                u16* __restrict__ wkvt,
                                                u16* __restrict__ wot,
                                                u16* __restrict__ w1i,
                                                u16* __restrict__ w2t, float qsc,
                                                const float* __restrict__ xq,
                                                const float* __restrict__ xkv,
                                                const float* __restrict__ scq,
                                                const float* __restrict__ biq,
                                                const float* __restrict__ sckv,
                                                const float* __restrict__ bikv,
                                                u16* __restrict__ outq,
                                                u16* __restrict__ outkv) {
  __shared__ u16 t[64][72];
  __shared__ float rs[4], rs2[4];
  const int id = blockIdx.x;
  const int tid = threadIdx.x;
  if (id >= 4096) {
    // ---- LayerNorm path ----
    const int rid = id - 4096;
    const bool isq = rid < 4096;
    const int row = isq ? rid : rid - 4096;
    const float* x = isq ? xq : xkv;
    const float* sc = isq ? scq : sckv;
    const float* bi = isq ? biq : bikv;
    u16* out = isq ? outq : outkv;
    float4 v = ((const float4*)(x + (size_t)row * 1024))[tid];
    float s = v.x + v.y + v.z + v.w;
    float s2 = v.x * v.x + v.y * v.y + v.z * v.z + v.w * v.w;
    for (int m = 1; m < 64; m <<= 1) {
      s += __shfl_xor(s, m);
      s2 += __shfl_xor(s2, m);
    }
    int wave = tid >> 6, lane = tid & 63;
    if (lane == 0) { rs[wave] = s; rs2[wave] = s2; }
    __syncthreads();
    s = rs[0] + rs[1] + rs[2] + rs[3];
    s2 = rs2[0] + rs2[1] + rs2[2] + rs2[3];
    float mu = s * (1.0f / 1024.0f);
    float var = s2 * (1.0f / 1024.0f) - mu * mu;
    float inv = rsqrtf(var + 1e-6f);
    float4 scv = ((const float4*)sc)[tid];
    float4 biv = ((const float4*)bi)[tid];
    s16x4 o;
    o[0] = (short)f2bf((v.x - mu) * inv * scv.x + biv.x);
    o[1] = (short)f2bf((v.y - mu) * inv * scv.y + biv.y);
    o[2] = (short)f2bf((v.z - mu) * inv * scv.z + biv.z);
    o[3] = (short)f2bf((v.w - mu) * inv * scv.w + biv.w);
    *(s16x4*)(out + (size_t)row * 1024 + tid * 4) = o;
    return;
  }
  auto tileT = [&](const float* in, u16* out, int K, int N, int k0, int n0, float scale) {
#pragma unroll
    for (int i = 0; i < 16; ++i) {
      int idx = tid + i * 256;
      int r = idx >> 6, c = idx & 63;
      t[r][c] = f2bf(in[(size_t)(k0 + r) * N + n0 + c] * scale);
    }
    __syncthreads();
#pragma unroll
    for (int i = 0; i < 16; ++i) {
      int idx = tid + i * 256;
      int r = idx >> 6, c = idx & 63;
      out[(size_t)(n0 + r) * K + k0 + c] = t[c][r];
    }
  };
  if (id < 256) {
    tileT(Wq, wqt, 1024, 1024, (id & 15) * 64, (id >> 4) * 64, qsc);
  } else if (id < 512) {
    int i2 = id - 256;
    tileT(Wk, wkvt, 1024, 1024, (i2 & 15) * 64, (i2 >> 4) * 64, 1.0f);
  } else if (id < 768) {
    int i2 = id - 512;
    tileT(Wv, wkvt + 1024 * 1024, 1024, 1024, (i2 & 15) * 64, (i2 >> 4) * 64, 1.0f);
  } else if (id < 1024) {
    int i2 = id - 768;
    tileT(Wo, wot, 1024, 1024, (i2 & 15) * 64, (i2 >> 4) * 64, 1.0f);
  } else if (id < 3072) {
    int i2 = id - 1024;
    int k0 = (i2 & 15) * 64, n0 = (i2 >> 4) * 64;
#pragma unroll
    for (int i = 0; i < 16; ++i) {
      int idx = tid + i * 256;
      int r = idx >> 6, c = idx & 63;
      int np = n0 + c;
      int orig = ((np >> 5) << 4) + (np & 15) + (((np >> 4) & 1) << 12);
      t[r][c] = f2bf(W1[(size_t)(k0 + r) * 8192 + orig]);
    }
    __syncthreads();
#pragma unroll
    for (int i = 0; i < 16; ++i) {
      int idx = tid + i * 256;
      int r = idx >> 6, c = idx & 63;
      w1i[(size_t)(n0 + r) * 1024 + k0 + c] = t[c][r];
    }
  } else {
    int i3 = id - 3072;
    tileT(W2, w2t, 4096, 1024, (i3 & 63) * 64, (i3 >> 6) * 64, 1.0f);
  }
}

// ---- standalone LN (used for ln2 only) ----
__global__ __launch_bounds__(256) void ln_fused(const float* __restrict__ xq,
                                                const float* __restrict__ sc,
                                                const float* __restrict__ bi,
                                                u16* __restrict__ out) {
  const int row = blockIdx.x;
  int tid = threadIdx.x;
  float4 v = ((const float4*)(xq + (size_t)row * 1024))[tid];
  float s = v.x + v.y + v.z + v.w;
  float s2 = v.x * v.x + v.y * v.y + v.z * v.z + v.w * v.w;
  for (int m = 1; m < 64; m <<= 1) {
    s += __shfl_xor(s, m);
    s2 += __shfl_xor(s2, m);
  }
  __shared__ float rs[4], rs2[4];
  int wave = tid >> 6, lane = tid & 63;
  if (lane == 0) { rs[wave] = s; rs2[wave] = s2; }
  __syncthreads();
  s = rs[0] + rs[1] + rs[2] + rs[3];
  s2 = rs2[0] + rs2[1] + rs2[2] + rs2[3];
  float mu = s * (1.0f / 1024.0f);
  float var = s2 * (1.0f / 1024.0f) - mu * mu;
  float inv = rsqrtf(var + 1e-6f);
  float4 scv = ((const float4*)sc)[tid];
  float4 biv = ((const float4*)bi)[tid];
  s16x4 o;
  o[0] = (short)f2bf((v.x - mu) * inv * scv.x + biv.x);
  o[1] = (short)f2bf((v.y - mu) * inv * scv.y + biv.y);
  o[2] = (short)f2bf((v.z - mu) * inv * scv.z + biv.z);
  o[3] = (short)f2bf((v.w - mu) * inv * scv.w + biv.w);
  *(s16x4*)(out + (size_t)row * 1024 + tid * 4) = o;
}

// ---- 128x128 GEMM: stage-ahead double-buffer (T3-minimum, m97 structure) ----
// MODE 0: bf16 row-major. MODE 2: f32 + resid.
template <int MODE>
__global__ __launch_bounds__(256) void gemm_nt(const u16* __restrict__ A,
                                               const u16* __restrict__ Bt,
                                               const float* __restrict__ bias,
                                               const float* __restrict__ resid,
                                               void* __restrict__ Cout,
                                               int M, int N, int K, float bias_scale) {
  __shared__ u16 As[2][128 * 64];
  __shared__ u16 Bs[2][128 * 64];
  const int nbx = gridDim.x;
  const int nwg = nbx * gridDim.y;
  const int wg0 = blockIdx.y * nbx + blockIdx.x;
  const int wg = (nwg & 7) ? wg0 : (wg0 & 7) * (nwg >> 3) + (wg0 >> 3);
  const int m0 = (wg % nbx) * 128, n0 = (wg / nbx) * 128;
  const int tid = threadIdx.x;
  const int lane = tid & 63, wave = tid >> 6;
  const int wm = (wave >> 1) * 64, wn = (wave & 1) * 64;
  const int lr = lane & 15, hi4 = lane >> 4;
  const int NT = K >> 6;
  auto stage = [&](int t, int buf) {
#pragma unroll
    for (int i = 0; i < 4; ++i) {
      int s = i * 256 + tid;
      int r = s >> 3, slot = s & 7;
      int gslot = slot ^ (r & 7);
      int ldst = (i * 256 + wave * 64) * 8;
      GLDS16(A + (size_t)(m0 + r) * K + t * 64 + gslot * 8, &As[buf][ldst]);
      GLDS16(Bt + (size_t)(n0 + r) * K + t * 64 + gslot * 8, &Bs[buf][ldst]);
    }
  };
  f32x4 acc[4][4] = {};
  stage(0, 0);
  asm volatile("s_waitcnt vmcnt(0)" ::: "memory");
  __builtin_amdgcn_s_barrier();
  int buf = 0;
  for (int t = 0; t < NT; ++t) {
    if (t + 1 < NT) stage(t + 1, buf ^ 1);  // prefetch hides under MFMA below
#pragma unroll
    for (int ks = 0; ks < 2; ++ks) {
      const int sl = ((ks * 4 + hi4) ^ (lr & 7)) * 8;
      bf16x8 af[4], bfr[4];
#pragma unroll
      for (int tt = 0; tt < 4; ++tt) {
        af[tt] = __builtin_bit_cast(bf16x8, *(const s16x8*)&As[buf][(wm + tt * 16 + lr) * 64 + sl]);
        bfr[tt] = __builtin_bit_cast(bf16x8, *(const s16x8*)&Bs[buf][(wn + tt * 16 + lr) * 64 + sl]);
      }
      __builtin_amdgcn_s_setprio(1);
#pragma unroll
      for (int mt = 0; mt < 4; ++mt)
#pragma unroll
        for (int nt = 0; nt < 4; ++nt)
          acc[mt][nt] = MFMA16(af[mt], bfr[nt], acc[mt][nt]);
      __builtin_amdgcn_s_setprio(0);
    }
    asm volatile("s_waitcnt vmcnt(0) lgkmcnt(0)" ::: "memory");
    __builtin_amdgcn_s_barrier();
    buf ^= 1;
  }
#pragma unroll
  for (int mt = 0; mt < 4; ++mt) {
#pragma unroll
    for (int nt = 0; nt < 4; ++nt) {
      const int ncol = n0 + wn + nt * 16 + lr;
      const float bv = bias[ncol] * bias_scale;
      const int mbase = m0 + wm + mt * 16 + hi4 * 4;
#pragma unroll
      for (int r = 0; r < 4; ++r) {
        const int m = mbase + r;
        const float val = acc[mt][nt][r] + bv;
        if constexpr (MODE == 0) {
          ((u16*)Cout)[(size_t)m * N + ncol] = f2bf(val);
        } else {
          ((float*)Cout)[(size_t)m * N + ncol] = val + resid[(size_t)m * N + ncol];
        }
      }
    }
  }
}

// ---- 256x256 8-phase deep-pipelined GEMM (counted vmcnt) ----
template <int MODE>
__global__ __launch_bounds__(512, 2) void gemm256(const u16* __restrict__ A,
                                                  const u16* __restrict__ Bt,
                                                  const float* __restrict__ bias,
                                                  const float* __restrict__ bias2,
                                                  u16* __restrict__ Cout,
                                                  u16* __restrict__ Vout,
                                                  int M, int N, int K, int nmajor) {
  __shared__ __align__(16) u16 sA[2][2][256 * 32];
  __shared__ __align__(16) u16 sB[2][2][256 * 32];
  const int nbx = M >> 8, nby = N >> 8;
  const int nblk = nbx * nby;
  const int cpx = nblk >> 3;
  const int wg0 = blockIdx.x;
  const int wg = (wg0 & 7) * cpx + (wg0 >> 3);
  int mi, ni;
  if (nmajor) { ni = wg % nby; mi = wg / nby; } else { mi = wg % nbx; ni = wg / nbx; }
  const int m0 = mi << 8, n0 = ni << 8;
  const int tid = threadIdx.x;
  const int lane = tid & 63, wave = tid >> 6;
  const int wr = wave >> 2, wc = wave & 3;
  const int lr = lane & 15, hi4 = lane >> 4;
  const int rdoct = (hi4 ^ ((lr >> 1) & 3)) * 8;
  const int NT = K >> 6;

  auto stageA = [&](int t, int kh) {
#pragma unroll
    for (int i = 0; i < 2; ++i) {
      int idx = i * 512 + tid;
      int r = idx >> 2, go = (idx & 3) ^ ((r >> 1) & 3);
      GLDS16(A + (size_t)(m0 + r) * K + t * 64 + kh * 32 + go * 8,
             &sA[t & 1][kh][(i * 512 + wave * 64) * 8]);
    }
  };
  auto stageB = [&](int t, int kh) {
#pragma unroll
    for (int i = 0; i < 2; ++i) {
      int idx = i * 512 + tid;
      int r = idx >> 2, go = (idx & 3) ^ ((r >> 1) & 3);
      GLDS16(Bt + (size_t)(n0 + r) * K + t * 64 + kh * 32 + go * 8,
             &sB[t & 1][kh][(i * 512 + wave * 64) * 8]);
    }
  };

  f32x4 acc[8][4] = {};
  bf16x8 af[4], bf[4];

  stageA(0, 0); stageB(0, 0); stageA(0, 1); stageB(0, 1);
  asm volatile("s_waitcnt vmcnt(4)" ::: "memory");
  __builtin_amdgcn_s_barrier();
  __builtin_amdgcn_sched_barrier(0);

  for (int t = 0; t < NT; ++t) {
    const int buf = t & 1;
    const bool pre = (t + 1 < NT);
#pragma unroll
    for (int kh = 0; kh < 2; ++kh) {
#pragma unroll
      for (int nt = 0; nt < 4; ++nt)
        bf[nt] = __builtin_bit_cast(bf16x8,
            *(const s16x8*)&sB[buf][kh][(wc * 64 + nt * 16 + lr) * 32 + rdoct]);
#pragma unroll
      for (int mf = 0; mf < 4; ++mf)
        af[mf] = __builtin_bit_cast(bf16x8,
            *(const s16x8*)&sA[buf][kh][(wr * 128 + mf * 16 + lr) * 32 + rdoct]);
      if (pre) stageA(t + 1, kh);
      __builtin_amdgcn_s_barrier();
      asm volatile("s_waitcnt lgkmcnt(0)" ::: "memory");
      __builtin_amdgcn_sched_barrier(0);
      __builtin_amdgcn_s_setprio(1);
#pragma unroll
      for (int mf = 0; mf < 4; ++mf)
#pragma unroll
        for (int nt = 0; nt < 4; ++nt)
          acc[mf][nt] = MFMA16(af[mf], bf[nt], acc[mf][nt]);
      __builtin_amdgcn_s_setprio(0);
      __builtin_amdgcn_s_barrier();
      __builtin_amdgcn_sched_barrier(0);
#pragma unroll
      for (int mf = 0; mf < 4; ++mf)
        af[mf] = __builtin_bit_cast(bf16x8,
            *(const s16x8*)&sA[buf][kh][(wr * 128 + (4 + mf) * 16 + lr) * 32 + rdoct]);
      if (pre) stageB(t + 1, kh);
      __builtin_amdgcn_s_barrier();
      asm volatile("s_waitcnt lgkmcnt(0)" ::: "memory");
      __builtin_amdgcn_sched_barrier(0);
      __builtin_amdgcn_s_setprio(1);
#pragma unroll
      for (int mf = 0; mf < 4; ++mf)
#pragma unroll
        for (int nt = 0; nt < 4; ++nt)
          acc[4 + mf][nt] = MFMA16(af[mf], bf[nt], acc[4 + mf][nt]);
      __builtin_amdgcn_s_setprio(0);
      if (pre)
        asm volatile("s_waitcnt vmcnt(4)" ::: "memory");
      else
        asm volatile("s_waitcnt vmcnt(0)" ::: "memory");
      __builtin_amdgcn_s_barrier();
      __builtin_amdgcn_sched_barrier(0);
    }
  }

  if constexpr (MODE == 0) {
#pragma unroll
    for (int mf = 0; mf < 8; ++mf) {
#pragma unroll
      for (int nt = 0; nt < 4; ++nt) {
        const int ncol = n0 + wc * 64 + nt * 16 + lr;
        const int mbase = m0 + wr * 128 + mf * 16 + hi4 * 4;
        const bool isk = ncol < 1024;
        const int vc = isk ? ncol : ncol - 1024;
        const float bv = isk ? bias[ncol] : bias2[vc];
#pragma unroll
        for (int r = 0; r < 4; ++r) {
          const int m = mbase + r;
          const float val = acc[mf][nt][r] + bv;
          if (isk) {
            Cout[(size_t)m * 1024 + ncol] = f2bf(val);
          } else {
            size_t vidx = ((size_t)((m >> 12) * 1024 + vc) << 12) | (size_t)(m & 4095);
            Vout[vidx] = f2bf(val);
          }
        }
      }
    }
  } else {
#pragma unroll
    for (int mf = 0; mf < 8; ++mf) {
      const int mbase = m0 + wr * 128 + mf * 16 + hi4 * 4;
#pragma unroll
      for (int p = 0; p < 2; ++p) {
        const int oc = (((n0 + wc * 64 + p * 32) >> 5) << 4) + lr;
        const float ba = bias[oc];
        const float bg = bias[oc + 4096];
#pragma unroll
        for (int r = 0; r < 4; ++r) {
          const int m = mbase + r;
          float a = acc[mf][2 * p][r] + ba;
          float g = acc[mf][2 * p + 1][r] + bg;
          Cout[(size_t)m * 4096 + oc] = f2bf(a * gelu_t(g));
        }
      }
    }
  }
}

// ---- flash attention: r4 structure + unroll-2 (compile-time LDS bases) + ones-MFMA lsum ----
__global__ __launch_bounds__(256, 2) void flash_attn(const u16* __restrict__ Qg,
                                                     const u16* __restrict__ Kg,
                                                     const u16* __restrict__ Vt,
                                                     u16* __restrict__ Og) {
  __shared__ u16 Ks[2][64 * 64];
  __shared__ u16 Vs[2][64 * 64];
  const int id = blockIdx.x;
  const int bh = (id & 7) * 4 + ((id >> 3) & 3);
  const int qb = id >> 5;
  const int b = bh >> 4, h = bh & 15;
  const int q0 = qb * 128;
  const int tid = threadIdx.x;
  const int lane = tid & 63, wave = tid >> 6;
  const int lq = lane & 31, hi = lane >> 5;
  const u16* Kbase = Kg + (size_t)(b * 4096) * 1024 + h * 64;
  const u16* Vbase = Vt + (size_t)((b * 16 + h) * 64) * 4096;
  bf16x8 qf[4];
  const size_t qrow = (size_t)(b * 2048 + q0 + wave * 32 + lq);
#pragma unroll
  for (int dc = 0; dc < 4; ++dc)
    qf[dc] = __builtin_bit_cast(bf16x8, *(const s16x8*)&Qg[qrow * 1024 + h * 64 + dc * 16 + hi * 8]);

  const u32x4 onesw = {0x3F803F80u, 0x3F803F80u, 0x3F803F80u, 0x3F803F80u};
  const bf16x8 ones = __builtin_bit_cast(bf16x8, onesw);
  f32x16 oacc0 = {}, oacc1 = {}, accl = {};

  auto stage = [&](int buf, int tile) {
    const int kv0 = tile * 64;
#pragma unroll
    for (int i = 0; i < 2; ++i) {
      int s = i * 256 + tid;
      int r = s >> 3;
      int inb = ((s & 7) * 16) ^ ((r & 7) << 4);
      GLDS16(Kbase + (size_t)(kv0 + r) * 1024 + (inb >> 1), &Ks[buf][(i * 256 + wave * 64) * 8]);
    }
#pragma unroll
    for (int i = 0; i < 2; ++i) {
      int s = i * 256 + tid;
      int r = s >> 3;
      int inb = ((s & 7) * 16) ^ ((r & 7) << 4);
      GLDS16(Vbase + (size_t)r * 4096 + kv0 + (inb >> 1), &Vs[buf][(i * 256 + wave * 64) * 8]);
    }
  };

  // one KV-tile: all LDS addresses are compile-time offsets from Kbuf/Vbuf
  auto computeT = [&](const u16* __restrict__ Kbuf, const u16* __restrict__ Vbuf) {
    f32x16 sA = {}, sB = {};
    __builtin_amdgcn_s_setprio(1);
#pragma unroll
    for (int dc = 0; dc < 4; ++dc) {
      int row = lq;
      int inb = (dc * 32 + hi * 16) ^ ((row & 7) << 4);
      bf16x8 kf = __builtin_bit_cast(bf16x8, *(const s16x8*)&Kbuf[row * 64 + (inb >> 1)]);
      sA = MFMA32(kf, qf[dc], sA);
    }
#pragma unroll
    for (int dc = 0; dc < 4; ++dc) {
      int row = 32 + lq;
      int inb = (dc * 32 + hi * 16) ^ ((row & 7) << 4);
      bf16x8 kf = __builtin_bit_cast(bf16x8, *(const s16x8*)&Kbuf[row * 64 + (inb >> 1)]);
      sB = MFMA32(kf, qf[dc], sB);
    }
    __builtin_amdgcn_s_setprio(0);
#pragma unroll
    for (int i = 0; i < 16; ++i) sA[i] = __builtin_amdgcn_exp2f(sA[i]);
#pragma unroll
    for (int i = 0; i < 16; ++i) sB[i] = __builtin_amdgcn_exp2f(sB[i]);
    u32 wa[8], wb[8];
#pragma unroll
    for (int i = 0; i < 8; ++i) wa[i] = cvtpk(sA[2 * i], sA[2 * i + 1]);
#pragma unroll
    for (int i = 0; i < 8; ++i) wb[i] = cvtpk(sB[2 * i], sB[2 * i + 1]);
    u32 a0 = wa[0], c0 = wa[2];
    asm("v_permlane32_swap_b32 %0, %1" : "+v"(a0), "+v"(c0));
    u32 a1 = wa[1], c1 = wa[3];
    asm("v_permlane32_swap_b32 %0, %1" : "+v"(a1), "+v"(c1));
    u32 a2 = wa[4], c2 = wa[6];
    asm("v_permlane32_swap_b32 %0, %1" : "+v"(a2), "+v"(c2));
    u32 a3 = wa[5], c3 = wa[7];
    asm("v_permlane32_swap_b32 %0, %1" : "+v"(a3), "+v"(c3));
    u32 e0 = wb[0], g0 = wb[2];
    asm("v_permlane32_swap_b32 %0, %1" : "+v"(e0), "+v"(g0));
    u32 e1 = wb[1], g1 = wb[3];
    asm("v_permlane32_swap_b32 %0, %1" : "+v"(e1), "+v"(g1));
    u32 e2 = wb[4], g2 = wb[6];
    asm("v_permlane32_swap_b32 %0, %1" : "+v"(e2), "+v"(g2));
    u32 e3 = wb[5], g3 = wb[7];
    asm("v_permlane32_swap_b32 %0, %1" : "+v"(e3), "+v"(g3));
    u32x4 t00 = {a0, a1, c0, c1};
    u32x4 t01 = {a2, a3, c2, c3};
    u32x4 t10 = {e0, e1, g0, g1};
    u32x4 t11 = {e2, e3, g2, g3};
    bf16x8 pf[4] = {__builtin_bit_cast(bf16x8, t00), __builtin_bit_cast(bf16x8, t01),
                    __builtin_bit_cast(bf16x8, t10), __builtin_bit_cast(bf16x8, t11)};
    __builtin_amdgcn_s_setprio(1);
#pragma unroll
    for (int st = 0; st < 2; ++st)
#pragma unroll
      for (int c = 0; c < 2; ++c) {
        const int pi = st * 2 + c;
        {
          int row = lq;
          int inb = (st * 64 + c * 32 + hi * 16) ^ ((row & 7) << 4);
          bf16x8 vf = __builtin_bit_cast(bf16x8, *(const s16x8*)&Vbuf[row * 64 + (inb >> 1)]);
          oacc0 = MFMA32(vf, pf[pi], oacc0);
        }
        {
          int row = 32 + lq;
          int inb = (st * 64 + c * 32 + hi * 16) ^ ((row & 7) << 4);
          bf16x8 vf = __builtin_bit_cast(bf16x8, *(const s16x8*)&Vbuf[row * 64 + (inb >> 1)]);
          oacc1 = MFMA32(vf, pf[pi], oacc1);
        }
        accl = MFMA32(ones, pf[pi], accl);  // l-sum on matrix pipe (verified r7/r8)
      }
    __builtin_amdgcn_s_setprio(0);
  };

  stage(0, 0);
  __syncthreads();
  for (int t = 0; t < 64; t += 2) {
    if (t + 1 < 64) stage(1, t + 1);
    computeT(Ks[0], Vs[0]);
    __syncthreads();
    if (t + 2 < 64) stage(0, t + 2);
    computeT(Ks[1], Vs[1]);
    __syncthreads();
  }
  float rinv = 1.0f / accl[0];
  u16* obase = Og + qrow * 1024 + h * 64;
#pragma unroll
  for (int rp = 0; rp < 8; ++rp) {
    int r0 = rp * 2;
    int d0 = (r0 & 3) + 8 * (r0 >> 2) + 4 * hi;
    *(u32*)&obase[d0] = cvtpk(oacc0[r0] * rinv, oacc0[r0 + 1] * rinv);
    *(u32*)&obase[32 + d0] = cvtpk(oacc1[r0] * rinv, oacc1[r0 + 1] * rinv);
  }
}

extern "C" void kernel_launch(void* const* d_in, const int* in_sizes, int n_in,
                              void* d_out, int out_size, void* d_ws, size_t ws_size,
                              hipStream_t stream) {
  (void)in_sizes; (void)n_in; (void)out_size; (void)ws_size;
  const float* inputs_q = (const float*)d_in[0];
  const float* inputs_kv = (const float*)d_in[1];
  const float* ln_q_scale = (const float*)d_in[2];
  const float* ln_q_bias = (const float*)d_in[3];
  const float* ln_kv_scale = (const float*)d_in[4];
  const float* ln_kv_bias = (const float*)d_in[5];
  const float* Wq = (const float*)d_in[6];
  const float* bq = (const float*)d_in[7];
  const float* Wk = (const float*)d_in[8];
  const float* bk = (const float*)d_in[9];
  const float* Wv = (const float*)d_in[10];
  const float* bv = (const float*)d_in[11];
  const float* Wo = (const float*)d_in[12];
  const float* bo = (const float*)d_in[13];
  const float* ln2_scale = (const float*)d_in[14];
  const float* ln2_bias = (const float*)d_in[15];
  const float* W1 = (const float*)d_in[16];
  const float* b1 = (const float*)d_in[17];
  const float* W2 = (const float*)d_in[18];
  const float* b2 = (const float*)d_in[19];
  float* out = (float*)d_out;
  char* ws = (char*)d_ws;
  const size_t MB = 1ull << 20;
  u16* lnq = (u16*)(ws + 0);
  u16* lnkv = (u16*)(ws + 8 * MB);
  u16* Qb = (u16*)(ws + 24 * MB);
  u16* Kb = (u16*)(ws + 32 * MB);
  u16* Vtb = (u16*)(ws + 48 * MB);
  u16* Ob = (u16*)(ws + 64 * MB);
  float* xbuf = (float*)(ws + 72 * MB);
  u16* ln2b = (u16*)(ws + 88 * MB);
  u16* gg = (u16*)(ws + 96 * MB);
  u16* wqt = (u16*)(ws + 128 * MB);
  u16* wkvt = (u16*)(ws + 130 * MB);
  u16* wot = (u16*)(ws + 134 * MB);
  u16* w1i = (u16*)(ws + 136 * MB);
  u16* w2t = (u16*)(ws + 152 * MB);

  const float QSC = 0.125f * 1.44269504088896f;
  dim3 blk(256);
  prep_all<<<dim3(16384), blk, 0, stream>>>(Wq, Wk, Wv, Wo, W1, W2, wqt, wkvt, wot, w1i, w2t, QSC,
                                            inputs_q, inputs_kv, ln_q_scale, ln_q_bias,
                                            ln_kv_scale, ln_kv_bias, lnq, lnkv);
  gemm_nt<0><<<dim3(32, 8), blk, 0, stream>>>(lnq, wqt, bq, nullptr, Qb, 4096, 1024, 1024, QSC);
  gemm256<0><<<dim3(256), dim3(512), 0, stream>>>(lnkv, wkvt, bk, bv, Kb, Vtb, 8192, 2048, 1024, 1);
  flash_attn<<<dim3(512), blk, 0, stream>>>(Qb, Kb, Vtb, Ob);
  gemm_nt<2><<<dim3(32, 8), blk, 0, stream>>>(Ob, wot, bo, inputs_q, xbuf, 4096, 1024, 1024, 1.0f);
  ln_fused<<<dim3(4096), blk, 0, stream>>>(xbuf, ln2_scale, ln2_bias, ln2b);
  gemm256<1><<<dim3(512), dim3(512), 0, stream>>>(ln2b, w1i, b1, nullptr, gg, nullptr, 4096, 8192, 1024, 0);
  gemm_nt<2><<<dim3(32, 8), blk, 0, stream>>>(gg, w2t, b2, xbuf, out, 4096, 1024, 4096, 1.0f);
}

// Round 12
// 352.353 us; speedup vs baseline: 1.1894x; 1.0691x over previous
//
#include <hip/hip_runtime.h>

typedef unsigned short u16;
typedef unsigned int u32;
typedef float f32x4 __attribute__((ext_vector_type(4)));
typedef float f32x16 __attribute__((ext_vector_type(16)));
typedef __bf16 bf16x8 __attribute__((ext_vector_type(8)));
typedef short s16x8 __attribute__((ext_vector_type(8)));
typedef short s16x4 __attribute__((ext_vector_type(4)));
typedef u32 u32x4 __attribute__((ext_vector_type(4)));

#define MFMA16(a, b, c) __builtin_amdgcn_mfma_f32_16x16x32_bf16((a), (b), (c), 0, 0, 0)
#define MFMA32(a, b, c) __builtin_amdgcn_mfma_f32_32x32x16_bf16((a), (b), (c), 0, 0, 0)

typedef const __attribute__((address_space(1))) void* gas1_t;
typedef __attribute__((address_space(3))) void* las3_t;
#define GLDS16(g, l) __builtin_amdgcn_global_load_lds((gas1_t)(g), (las3_t)(l), 16, 0, 0)

static __device__ __forceinline__ u16 f2bf(float f) {
  u32 u = __builtin_bit_cast(u32, f);
  u += 0x7FFFu + ((u >> 16) & 1u);
  return (u16)(u >> 16);
}
static __device__ __forceinline__ u32 cvtpk(float lo, float hi) {
  u32 r;
  asm("v_cvt_pk_bf16_f32 %0, %1, %2" : "=v"(r) : "v"(lo), "v"(hi));
  return r;
}
static __device__ __forceinline__ float gelu_t(float g) {
  float u = 0.7978845608f * (g + 0.044715f * g * g * g);
  float e = __expf(2.0f * u);
  float t = 1.0f - 2.0f / (e + 1.0f);
  return 0.5f * g * (1.0f + t);
}

// ---- ALL weight preprocessing + input LayerNorms in ONE launch (16384 blocks) ----
__global__ __launch_bounds__(256) void prep_all(const float* __restrict__ Wq,
                                                const float* __restrict__ Wk,
                                                const float* __restrict__ Wv,
                                                const float* __restrict__ Wo,
                                                const float* __restrict__ W1,
                                                const float* __restrict__ W2,
                                                u16* __restrict__ wqt,
                                                u16* __restrict__ wkvt,
                                                u16* __restrict__ wot,
                                                u16* __restrict__ w1i,
                                                u16* __restrict__ w2t, float qsc,
                                                const float* __restrict__ xq,
                                                const float* __restrict__ xkv,
                                                const float* __restrict__ scq,
                                                const float* __restrict__ biq,
                                                const float* __restrict__ sckv,
                                                const float* __restrict__ bikv,
                                                u16* __restrict__ outq,
                                                u16* __restrict__ outkv) {
  __shared__ u16 t[64][72];
  __shared__ float rs[4], rs2[4];
  const int id = blockIdx.x;
  const int tid = threadIdx.x;
  if (id >= 4096) {
    const int rid = id - 4096;
    const bool isq = rid < 4096;
    const int row = isq ? rid : rid - 4096;
    const float* x = isq ? xq : xkv;
    const float* sc = isq ? scq : sckv;
    const float* bi = isq ? biq : bikv;
    u16* out = isq ? outq : outkv;
    float4 v = ((const float4*)(x + (size_t)row * 1024))[tid];
    float s = v.x + v.y + v.z + v.w;
    float s2 = v.x * v.x + v.y * v.y + v.z * v.z + v.w * v.w;
    for (int m = 1; m < 64; m <<= 1) {
      s += __shfl_xor(s, m);
      s2 += __shfl_xor(s2, m);
    }
    int wave = tid >> 6, lane = tid & 63;
    if (lane == 0) { rs[wave] = s; rs2[wave] = s2; }
    __syncthreads();
    s = rs[0] + rs[1] + rs[2] + rs[3];
    s2 = rs2[0] + rs2[1] + rs2[2] + rs2[3];
    float mu = s * (1.0f / 1024.0f);
    float var = s2 * (1.0f / 1024.0f) - mu * mu;
    float inv = rsqrtf(var + 1e-6f);
    float4 scv = ((const float4*)sc)[tid];
    float4 biv = ((const float4*)bi)[tid];
    s16x4 o;
    o[0] = (short)f2bf((v.x - mu) * inv * scv.x + biv.x);
    o[1] = (short)f2bf((v.y - mu) * inv * scv.y + biv.y);
    o[2] = (short)f2bf((v.z - mu) * inv * scv.z + biv.z);
    o[3] = (short)f2bf((v.w - mu) * inv * scv.w + biv.w);
    *(s16x4*)(out + (size_t)row * 1024 + tid * 4) = o;
    return;
  }
  auto tileT = [&](const float* in, u16* out, int K, int N, int k0, int n0, float scale) {
#pragma unroll
    for (int i = 0; i < 16; ++i) {
      int idx = tid + i * 256;
      int r = idx >> 6, c = idx & 63;
      t[r][c] = f2bf(in[(size_t)(k0 + r) * N + n0 + c] * scale);
    }
    __syncthreads();
#pragma unroll
    for (int i = 0; i < 16; ++i) {
      int idx = tid + i * 256;
      int r = idx >> 6, c = idx & 63;
      out[(size_t)(n0 + r) * K + k0 + c] = t[c][r];
    }
  };
  if (id < 256) {
    tileT(Wq, wqt, 1024, 1024, (id & 15) * 64, (id >> 4) * 64, qsc);
  } else if (id < 512) {
    int i2 = id - 256;
    tileT(Wk, wkvt, 1024, 1024, (i2 & 15) * 64, (i2 >> 4) * 64, 1.0f);
  } else if (id < 768) {
    int i2 = id - 512;
    tileT(Wv, wkvt + 1024 * 1024, 1024, 1024, (i2 & 15) * 64, (i2 >> 4) * 64, 1.0f);
  } else if (id < 1024) {
    int i2 = id - 768;
    tileT(Wo, wot, 1024, 1024, (i2 & 15) * 64, (i2 >> 4) * 64, 1.0f);
  } else if (id < 3072) {
    int i2 = id - 1024;
    int k0 = (i2 & 15) * 64, n0 = (i2 >> 4) * 64;
#pragma unroll
    for (int i = 0; i < 16; ++i) {
      int idx = tid + i * 256;
      int r = idx >> 6, c = idx & 63;
      int np = n0 + c;
      int orig = ((np >> 5) << 4) + (np & 15) + (((np >> 4) & 1) << 12);
      t[r][c] = f2bf(W1[(size_t)(k0 + r) * 8192 + orig]);
    }
    __syncthreads();
#pragma unroll
    for (int i = 0; i < 16; ++i) {
      int idx = tid + i * 256;
      int r = idx >> 6, c = idx & 63;
      w1i[(size_t)(n0 + r) * 1024 + k0 + c] = t[c][r];
    }
  } else {
    int i3 = id - 3072;
    tileT(W2, w2t, 4096, 1024, (i3 & 63) * 64, (i3 >> 6) * 64, 1.0f);
  }
}

// ---- standalone LN (ln2) ----
__global__ __launch_bounds__(256) void ln_fused(const float* __restrict__ xq,
                                                const float* __restrict__ sc,
                                                const float* __restrict__ bi,
                                                u16* __restrict__ out) {
  const int row = blockIdx.x;
  int tid = threadIdx.x;
  float4 v = ((const float4*)(xq + (size_t)row * 1024))[tid];
  float s = v.x + v.y + v.z + v.w;
  float s2 = v.x * v.x + v.y * v.y + v.z * v.z + v.w * v.w;
  for (int m = 1; m < 64; m <<= 1) {
    s += __shfl_xor(s, m);
    s2 += __shfl_xor(s2, m);
  }
  __shared__ float rs[4], rs2[4];
  int wave = tid >> 6, lane = tid & 63;
  if (lane == 0) { rs[wave] = s; rs2[wave] = s2; }
  __syncthreads();
  s = rs[0] + rs[1] + rs[2] + rs[3];
  s2 = rs2[0] + rs2[1] + rs2[2] + rs2[3];
  float mu = s * (1.0f / 1024.0f);
  float var = s2 * (1.0f / 1024.0f) - mu * mu;
  float inv = rsqrtf(var + 1e-6f);
  float4 scv = ((const float4*)sc)[tid];
  float4 biv = ((const float4*)bi)[tid];
  s16x4 o;
  o[0] = (short)f2bf((v.x - mu) * inv * scv.x + biv.x);
  o[1] = (short)f2bf((v.y - mu) * inv * scv.y + biv.y);
  o[2] = (short)f2bf((v.z - mu) * inv * scv.z + biv.z);
  o[3] = (short)f2bf((v.w - mu) * inv * scv.w + biv.w);
  *(s16x4*)(out + (size_t)row * 1024 + tid * 4) = o;
}

// ---- 128x128 GEMM: stage-ahead double-buffer ----
template <int MODE>
__global__ __launch_bounds__(256) void gemm_nt(const u16* __restrict__ A,
                                               const u16* __restrict__ Bt,
                                               const float* __restrict__ bias,
                                               const float* __restrict__ resid,
                                               void* __restrict__ Cout,
                                               int M, int N, int K, float bias_scale) {
  __shared__ u16 As[2][128 * 64];
  __shared__ u16 Bs[2][128 * 64];
  const int nbx = gridDim.x;
  const int nwg = nbx * gridDim.y;
  const int wg0 = blockIdx.y * nbx + blockIdx.x;
  const int wg = (nwg & 7) ? wg0 : (wg0 & 7) * (nwg >> 3) + (wg0 >> 3);
  const int m0 = (wg % nbx) * 128, n0 = (wg / nbx) * 128;
  const int tid = threadIdx.x;
  const int lane = tid & 63, wave = tid >> 6;
  const int wm = (wave >> 1) * 64, wn = (wave & 1) * 64;
  const int lr = lane & 15, hi4 = lane >> 4;
  const int NT = K >> 6;
  auto stage = [&](int t, int buf) {
#pragma unroll
    for (int i = 0; i < 4; ++i) {
      int s = i * 256 + tid;
      int r = s >> 3, slot = s & 7;
      int gslot = slot ^ (r & 7);
      int ldst = (i * 256 + wave * 64) * 8;
      GLDS16(A + (size_t)(m0 + r) * K + t * 64 + gslot * 8, &As[buf][ldst]);
      GLDS16(Bt + (size_t)(n0 + r) * K + t * 64 + gslot * 8, &Bs[buf][ldst]);
    }
  };
  f32x4 acc[4][4] = {};
  stage(0, 0);
  asm volatile("s_waitcnt vmcnt(0)" ::: "memory");
  __builtin_amdgcn_s_barrier();
  int buf = 0;
  for (int t = 0; t < NT; ++t) {
    if (t + 1 < NT) stage(t + 1, buf ^ 1);
#pragma unroll
    for (int ks = 0; ks < 2; ++ks) {
      const int sl = ((ks * 4 + hi4) ^ (lr & 7)) * 8;
      bf16x8 af[4], bfr[4];
#pragma unroll
      for (int tt = 0; tt < 4; ++tt) {
        af[tt] = __builtin_bit_cast(bf16x8, *(const s16x8*)&As[buf][(wm + tt * 16 + lr) * 64 + sl]);
        bfr[tt] = __builtin_bit_cast(bf16x8, *(const s16x8*)&Bs[buf][(wn + tt * 16 + lr) * 64 + sl]);
      }
      __builtin_amdgcn_s_setprio(1);
#pragma unroll
      for (int mt = 0; mt < 4; ++mt)
#pragma unroll
        for (int nt = 0; nt < 4; ++nt)
          acc[mt][nt] = MFMA16(af[mt], bfr[nt], acc[mt][nt]);
      __builtin_amdgcn_s_setprio(0);
    }
    asm volatile("s_waitcnt vmcnt(0) lgkmcnt(0)" ::: "memory");
    __builtin_amdgcn_s_barrier();
    buf ^= 1;
  }
#pragma unroll
  for (int mt = 0; mt < 4; ++mt) {
#pragma unroll
    for (int nt = 0; nt < 4; ++nt) {
      const int ncol = n0 + wn + nt * 16 + lr;
      const float bv = bias[ncol] * bias_scale;
      const int mbase = m0 + wm + mt * 16 + hi4 * 4;
#pragma unroll
      for (int r = 0; r < 4; ++r) {
        const int m = mbase + r;
        const float val = acc[mt][nt][r] + bv;
        if constexpr (MODE == 0) {
          ((u16*)Cout)[(size_t)m * N + ncol] = f2bf(val);
        } else {
          ((float*)Cout)[(size_t)m * N + ncol] = val + resid[(size_t)m * N + ncol];
        }
      }
    }
  }
}

// ---- 256x256 8-phase deep-pipelined GEMM (counted vmcnt) ----
// MODE 0: KV-split; V-blocks (n0>=1024) use per-wave LDS-transpose epilogue for
// coalesced V^T writes (raw scatter was 2B @ 8KB stride = heavy write amplification).
// MODE 1: GEGLU epilogue.
template <int MODE>
__global__ __launch_bounds__(512, 2) void gemm256(const u16* __restrict__ A,
                                                  const u16* __restrict__ Bt,
                                                  const float* __restrict__ bias,
                                                  const float* __restrict__ bias2,
                                                  u16* __restrict__ Cout,
                                                  u16* __restrict__ Vout,
                                                  int M, int N, int K, int nmajor) {
  __shared__ __align__(16) u16 sA[2][2][256 * 32];
  __shared__ __align__(16) u16 sB[2][2][256 * 32];
  const int nbx = M >> 8, nby = N >> 8;
  const int nblk = nbx * nby;
  const int cpx = nblk >> 3;
  const int wg0 = blockIdx.x;
  const int wg = (wg0 & 7) * cpx + (wg0 >> 3);
  int mi, ni;
  if (nmajor) { ni = wg % nby; mi = wg / nby; } else { mi = wg % nbx; ni = wg / nbx; }
  const int m0 = mi << 8, n0 = ni << 8;
  const int tid = threadIdx.x;
  const int lane = tid & 63, wave = tid >> 6;
  const int wr = wave >> 2, wc = wave & 3;
  const int lr = lane & 15, hi4 = lane >> 4;
  const int rdoct = (hi4 ^ ((lr >> 1) & 3)) * 8;
  const int NT = K >> 6;

  auto stageA = [&](int t, int kh) {
#pragma unroll
    for (int i = 0; i < 2; ++i) {
      int idx = i * 512 + tid;
      int r = idx >> 2, go = (idx & 3) ^ ((r >> 1) & 3);
      GLDS16(A + (size_t)(m0 + r) * K + t * 64 + kh * 32 + go * 8,
             &sA[t & 1][kh][(i * 512 + wave * 64) * 8]);
    }
  };
  auto stageB = [&](int t, int kh) {
#pragma unroll
    for (int i = 0; i < 2; ++i) {
      int idx = i * 512 + tid;
      int r = idx >> 2, go = (idx & 3) ^ ((r >> 1) & 3);
      GLDS16(Bt + (size_t)(n0 + r) * K + t * 64 + kh * 32 + go * 8,
             &sB[t & 1][kh][(i * 512 + wave * 64) * 8]);
    }
  };

  f32x4 acc[8][4] = {};
  bf16x8 af[4], bf[4];

  stageA(0, 0); stageB(0, 0); stageA(0, 1); stageB(0, 1);
  asm volatile("s_waitcnt vmcnt(4)" ::: "memory");
  __builtin_amdgcn_s_barrier();
  __builtin_amdgcn_sched_barrier(0);

  for (int t = 0; t < NT; ++t) {
    const int buf = t & 1;
    const bool pre = (t + 1 < NT);
#pragma unroll
    for (int kh = 0; kh < 2; ++kh) {
#pragma unroll
      for (int nt = 0; nt < 4; ++nt)
        bf[nt] = __builtin_bit_cast(bf16x8,
            *(const s16x8*)&sB[buf][kh][(wc * 64 + nt * 16 + lr) * 32 + rdoct]);
#pragma unroll
      for (int mf = 0; mf < 4; ++mf)
        af[mf] = __builtin_bit_cast(bf16x8,
            *(const s16x8*)&sA[buf][kh][(wr * 128 + mf * 16 + lr) * 32 + rdoct]);
      if (pre) stageA(t + 1, kh);
      __builtin_amdgcn_s_barrier();
      asm volatile("s_waitcnt lgkmcnt(0)" ::: "memory");
      __builtin_amdgcn_sched_barrier(0);
      __builtin_amdgcn_s_setprio(1);
#pragma unroll
      for (int mf = 0; mf < 4; ++mf)
#pragma unroll
        for (int nt = 0; nt < 4; ++nt)
          acc[mf][nt] = MFMA16(af[mf], bf[nt], acc[mf][nt]);
      __builtin_amdgcn_s_setprio(0);
      __builtin_amdgcn_s_barrier();
      __builtin_amdgcn_sched_barrier(0);
#pragma unroll
      for (int mf = 0; mf < 4; ++mf)
        af[mf] = __builtin_bit_cast(bf16x8,
            *(const s16x8*)&sA[buf][kh][(wr * 128 + (4 + mf) * 16 + lr) * 32 + rdoct]);
      if (pre) stageB(t + 1, kh);
      __builtin_amdgcn_s_barrier();
      asm volatile("s_waitcnt lgkmcnt(0)" ::: "memory");
      __builtin_amdgcn_sched_barrier(0);
      __builtin_amdgcn_s_setprio(1);
#pragma unroll
      for (int mf = 0; mf < 4; ++mf)
#pragma unroll
        for (int nt = 0; nt < 4; ++nt)
          acc[4 + mf][nt] = MFMA16(af[mf], bf[nt], acc[4 + mf][nt]);
      __builtin_amdgcn_s_setprio(0);
      if (pre)
        asm volatile("s_waitcnt vmcnt(4)" ::: "memory");
      else
        asm volatile("s_waitcnt vmcnt(0)" ::: "memory");
      __builtin_amdgcn_s_barrier();
      __builtin_amdgcn_sched_barrier(0);
    }
  }

  if constexpr (MODE == 0) {
    if (n0 >= 1024) {
      // ---- V path: per-wave LDS transpose -> coalesced 16B V^T stores ----
      // buffer [64 vc][40 u16] per wave (stride 40 keeps b128 16B-aligned); 4 passes x 32 m
      u16* wbuf = ((u16*)sA) + wave * (64 * 40);
      const int vcw = (n0 - 1024) + wc * 64;                    // wave's first V column
      const size_t vtrow0 = (size_t)((m0 >> 12) * 1024 + vcw);  // V^T row base
      const int colbase = (m0 & 4095) + wr * 128;               // V^T col base (m)
#pragma unroll
      for (int p = 0; p < 4; ++p) {
#pragma unroll
        for (int mfh = 0; mfh < 2; ++mfh) {
          const int mf = 2 * p + mfh;
#pragma unroll
          for (int nt = 0; nt < 4; ++nt) {
            const int cr = nt * 16 + lr;
            const float bvv = bias2[vcw + cr];
            const int mrr = mfh * 16 + hi4 * 4;
            *(u32*)&wbuf[cr * 40 + mrr] = cvtpk(acc[mf][nt][0] + bvv, acc[mf][nt][1] + bvv);
            *(u32*)&wbuf[cr * 40 + mrr + 2] = cvtpk(acc[mf][nt][2] + bvv, acc[mf][nt][3] + bvv);
          }
        }
        asm volatile("s_waitcnt lgkmcnt(0)" ::: "memory");
        __builtin_amdgcn_sched_barrier(0);
#pragma unroll
        for (int j = 0; j < 4; ++j) {
          const int row = j * 16 + (lane >> 2);  // 16 rows/iter, 4 lanes x 16B = 64B per row
          const int chunk = lane & 3;
          u32x4 v4 = *(const u32x4*)&wbuf[row * 40 + chunk * 8];
          *(u32x4*)&Vout[(vtrow0 + row) * 4096 + colbase + p * 32 + chunk * 8] = v4;
        }
        asm volatile("s_waitcnt lgkmcnt(0)" ::: "memory");  // reads done before next pass overwrites
        __builtin_amdgcn_sched_barrier(0);
      }
    } else {
      // ---- K path: row-major ----
#pragma unroll
      for (int mf = 0; mf < 8; ++mf) {
#pragma unroll
        for (int nt = 0; nt < 4; ++nt) {
          const int ncol = n0 + wc * 64 + nt * 16 + lr;
          const int mbase = m0 + wr * 128 + mf * 16 + hi4 * 4;
          const float bv = bias[ncol];
#pragma unroll
          for (int r = 0; r < 4; ++r) {
            const int m = mbase + r;
            Cout[(size_t)m * 1024 + ncol] = f2bf(acc[mf][nt][r] + bv);
          }
        }
      }
    }
  } else {
#pragma unroll
    for (int mf = 0; mf < 8; ++mf) {
      const int mbase = m0 + wr * 128 + mf * 16 + hi4 * 4;
#pragma unroll
      for (int p = 0; p < 2; ++p) {
        const int oc = (((n0 + wc * 64 + p * 32) >> 5) << 4) + lr;
        const float ba = bias[oc];
        const float bg = bias[oc + 4096];
#pragma unroll
        for (int r = 0; r < 4; ++r) {
          const int m = mbase + r;
          float a = acc[mf][2 * p][r] + ba;
          float g = acc[mf][2 * p + 1][r] + bg;
          Cout[(size_t)m * 4096 + oc] = f2bf(a * gelu_t(g));
        }
      }
    }
  }
}

// ---- flash attention (stable 89us structure; untouched) ----
__global__ __launch_bounds__(256, 2) void flash_attn(const u16* __restrict__ Qg,
                                                     const u16* __restrict__ Kg,
                                                     const u16* __restrict__ Vt,
                                                     u16* __restrict__ Og) {
  __shared__ u16 Ks[2][64 * 64];
  __shared__ u16 Vs[2][64 * 64];
  const int id = blockIdx.x;
  const int bh = (id & 7) * 4 + ((id >> 3) & 3);
  const int qb = id >> 5;
  const int b = bh >> 4, h = bh & 15;
  const int q0 = qb * 128;
  const int tid = threadIdx.x;
  const int lane = tid & 63, wave = tid >> 6;
  const int lq = lane & 31, hi = lane >> 5;
  const u16* Kbase = Kg + (size_t)(b * 4096) * 1024 + h * 64;
  const u16* Vbase = Vt + (size_t)((b * 16 + h) * 64) * 4096;
  bf16x8 qf[4];
  const size_t qrow = (size_t)(b * 2048 + q0 + wave * 32 + lq);
#pragma unroll
  for (int dc = 0; dc < 4; ++dc)
    qf[dc] = __builtin_bit_cast(bf16x8, *(const s16x8*)&Qg[qrow * 1024 + h * 64 + dc * 16 + hi * 8]);

  const u32x4 onesw = {0x3F803F80u, 0x3F803F80u, 0x3F803F80u, 0x3F803F80u};
  const bf16x8 ones = __builtin_bit_cast(bf16x8, onesw);
  f32x16 oacc0 = {}, oacc1 = {}, accl = {};

  auto stage = [&](int buf, int tile) {
    const int kv0 = tile * 64;
#pragma unroll
    for (int i = 0; i < 2; ++i) {
      int s = i * 256 + tid;
      int r = s >> 3;
      int inb = ((s & 7) * 16) ^ ((r & 7) << 4);
      GLDS16(Kbase + (size_t)(kv0 + r) * 1024 + (inb >> 1), &Ks[buf][(i * 256 + wave * 64) * 8]);
    }
#pragma unroll
    for (int i = 0; i < 2; ++i) {
      int s = i * 256 + tid;
      int r = s >> 3;
      int inb = ((s & 7) * 16) ^ ((r & 7) << 4);
      GLDS16(Vbase + (size_t)r * 4096 + kv0 + (inb >> 1), &Vs[buf][(i * 256 + wave * 64) * 8]);
    }
  };

  auto computeT = [&](const u16* __restrict__ Kbuf, const u16* __restrict__ Vbuf) {
    f32x16 sA = {}, sB = {};
    __builtin_amdgcn_s_setprio(1);
#pragma unroll
    for (int dc = 0; dc < 4; ++dc) {
      int row = lq;
      int inb = (dc * 32 + hi * 16) ^ ((row & 7) << 4);
      bf16x8 kf = __builtin_bit_cast(bf16x8, *(const s16x8*)&Kbuf[row * 64 + (inb >> 1)]);
      sA = MFMA32(kf, qf[dc], sA);
    }
#pragma unroll
    for (int dc = 0; dc < 4; ++dc) {
      int row = 32 + lq;
      int inb = (dc * 32 + hi * 16) ^ ((row & 7) << 4);
      bf16x8 kf = __builtin_bit_cast(bf16x8, *(const s16x8*)&Kbuf[row * 64 + (inb >> 1)]);
      sB = MFMA32(kf, qf[dc], sB);
    }
    __builtin_amdgcn_s_setprio(0);
#pragma unroll
    for (int i = 0; i < 16; ++i) sA[i] = __builtin_amdgcn_exp2f(sA[i]);
#pragma unroll
    for (int i = 0; i < 16; ++i) sB[i] = __builtin_amdgcn_exp2f(sB[i]);
    u32 wa[8], wb[8];
#pragma unroll
    for (int i = 0; i < 8; ++i) wa[i] = cvtpk(sA[2 * i], sA[2 * i + 1]);
#pragma unroll
    for (int i = 0; i < 8; ++i) wb[i] = cvtpk(sB[2 * i], sB[2 * i + 1]);
    u32 a0 = wa[0], c0 = wa[2];
    asm("v_permlane32_swap_b32 %0, %1" : "+v"(a0), "+v"(c0));
    u32 a1 = wa[1], c1 = wa[3];
    asm("v_permlane32_swap_b32 %0, %1" : "+v"(a1), "+v"(c1));
    u32 a2 = wa[4], c2 = wa[6];
    asm("v_permlane32_swap_b32 %0, %1" : "+v"(a2), "+v"(c2));
    u32 a3 = wa[5], c3 = wa[7];
    asm("v_permlane32_swap_b32 %0, %1" : "+v"(a3), "+v"(c3));
    u32 e0 = wb[0], g0 = wb[2];
    asm("v_permlane32_swap_b32 %0, %1" : "+v"(e0), "+v"(g0));
    u32 e1 = wb[1], g1 = wb[3];
    asm("v_permlane32_swap_b32 %0, %1" : "+v"(e1), "+v"(g1));
    u32 e2 = wb[4], g2 = wb[6];
    asm("v_permlane32_swap_b32 %0, %1" : "+v"(e2), "+v"(g2));
    u32 e3 = wb[5], g3 = wb[7];
    asm("v_permlane32_swap_b32 %0, %1" : "+v"(e3), "+v"(g3));
    u32x4 t00 = {a0, a1, c0, c1};
    u32x4 t01 = {a2, a3, c2, c3};
    u32x4 t10 = {e0, e1, g0, g1};
    u32x4 t11 = {e2, e3, g2, g3};
    bf16x8 pf[4] = {__builtin_bit_cast(bf16x8, t00), __builtin_bit_cast(bf16x8, t01),
                    __builtin_bit_cast(bf16x8, t10), __builtin_bit_cast(bf16x8, t11)};
    __builtin_amdgcn_s_setprio(1);
#pragma unroll
    for (int st = 0; st < 2; ++st)
#pragma unroll
      for (int c = 0; c < 2; ++c) {
        const int pi = st * 2 + c;
        {
          int row = lq;
          int inb = (st * 64 + c * 32 + hi * 16) ^ ((row & 7) << 4);
          bf16x8 vf = __builtin_bit_cast(bf16x8, *(const s16x8*)&Vbuf[row * 64 + (inb >> 1)]);
          oacc0 = MFMA32(vf, pf[pi], oacc0);
        }
        {
          int row = 32 + lq;
          int inb = (st * 64 + c * 32 + hi * 16) ^ ((row & 7) << 4);
          bf16x8 vf = __builtin_bit_cast(bf16x8, *(const s16x8*)&Vbuf[row * 64 + (inb >> 1)]);
          oacc1 = MFMA32(vf, pf[pi], oacc1);
        }
        accl = MFMA32(ones, pf[pi], accl);
      }
    __builtin_amdgcn_s_setprio(0);
  };

  stage(0, 0);
  __syncthreads();
  for (int t = 0; t < 64; t += 2) {
    if (t + 1 < 64) stage(1, t + 1);
    computeT(Ks[0], Vs[0]);
    __syncthreads();
    if (t + 2 < 64) stage(0, t + 2);
    computeT(Ks[1], Vs[1]);
    __syncthreads();
  }
  float rinv = 1.0f / accl[0];
  u16* obase = Og + qrow * 1024 + h * 64;
#pragma unroll
  for (int rp = 0; rp < 8; ++rp) {
    int r0 = rp * 2;
    int d0 = (r0 & 3) + 8 * (r0 >> 2) + 4 * hi;
    *(u32*)&obase[d0] = cvtpk(oacc0[r0] * rinv, oacc0[r0 + 1] * rinv);
    *(u32*)&obase[32 + d0] = cvtpk(oacc1[r0] * rinv, oacc1[r0 + 1] * rinv);
  }
}

extern "C" void kernel_launch(void* const* d_in, const int* in_sizes, int n_in,
                              void* d_out, int out_size, void* d_ws, size_t ws_size,
                              hipStream_t stream) {
  (void)in_sizes; (void)n_in; (void)out_size; (void)ws_size;
  const float* inputs_q = (const float*)d_in[0];
  const float* inputs_kv = (const float*)d_in[1];
  const float* ln_q_scale = (const float*)d_in[2];
  const float* ln_q_bias = (const float*)d_in[3];
  const float* ln_kv_scale = (const float*)d_in[4];
  const float* ln_kv_bias = (const float*)d_in[5];
  const float* Wq = (const float*)d_in[6];
  const float* bq = (const float*)d_in[7];
  const float* Wk = (const float*)d_in[8];
  const float* bk = (const float*)d_in[9];
  const float* Wv = (const float*)d_in[10];
  const float* bv = (const float*)d_in[11];
  const float* Wo = (const float*)d_in[12];
  const float* bo = (const float*)d_in[13];
  const float* ln2_scale = (const float*)d_in[14];
  const float* ln2_bias = (const float*)d_in[15];
  const float* W1 = (const float*)d_in[16];
  const float* b1 = (const float*)d_in[17];
  const float* W2 = (const float*)d_in[18];
  const float* b2 = (const float*)d_in[19];
  float* out = (float*)d_out;
  char* ws = (char*)d_ws;
  const size_t MB = 1ull << 20;
  u16* lnq = (u16*)(ws + 0);
  u16* lnkv = (u16*)(ws + 8 * MB);
  u16* Qb = (u16*)(ws + 24 * MB);
  u16* Kb = (u16*)(ws + 32 * MB);
  u16* Vtb = (u16*)(ws + 48 * MB);
  u16* Ob = (u16*)(ws + 64 * MB);
  float* xbuf = (float*)(ws + 72 * MB);
  u16* ln2b = (u16*)(ws + 88 * MB);
  u16* gg = (u16*)(ws + 96 * MB);
  u16* wqt = (u16*)(ws + 128 * MB);
  u16* wkvt = (u16*)(ws + 130 * MB);
  u16* wot = (u16*)(ws + 134 * MB);
  u16* w1i = (u16*)(ws + 136 * MB);
  u16* w2t = (u16*)(ws + 152 * MB);

  const float QSC = 0.125f * 1.44269504088896f;
  dim3 blk(256);
  prep_all<<<dim3(16384), blk, 0, stream>>>(Wq, Wk, Wv, Wo, W1, W2, wqt, wkvt, wot, w1i, w2t, QSC,
                                            inputs_q, inputs_kv, ln_q_scale, ln_q_bias,
                                            ln_kv_scale, ln_kv_bias, lnq, lnkv);
  gemm_nt<0><<<dim3(32, 8), blk, 0, stream>>>(lnq, wqt, bq, nullptr, Qb, 4096, 1024, 1024, QSC);
  gemm256<0><<<dim3(256), dim3(512), 0, stream>>>(lnkv, wkvt, bk, bv, Kb, Vtb, 8192, 2048, 1024, 1);
  flash_attn<<<dim3(512), blk, 0, stream>>>(Qb, Kb, Vtb, Ob);
  gemm_nt<2><<<dim3(32, 8), blk, 0, stream>>>(Ob, wot, bo, inputs_q, xbuf, 4096, 1024, 1024, 1.0f);
  ln_fused<<<dim3(4096), blk, 0, stream>>>(xbuf, ln2_scale, ln2_bias, ln2b);
  gemm256<1><<<dim3(512), dim3(512), 0, stream>>>(ln2b, w1i, b1, nullptr, gg, nullptr, 4096, 8192, 1024, 0);
  gemm_nt<2><<<dim3(32, 8), blk, 0, stream>>>(gg, w2t, b2, xbuf, out, 4096, 1024, 4096, 1.0f);
}